// Round 10
// baseline (1753.928 us; speedup 1.0000x reference)
//
#include <hip/hip_runtime.h>
#include <math.h>

#define B_ 8
#define N_ 4096
#define C_ 768
#define H_ 3072
#define M_ (B_*N_)
#define NSPLIT 16

typedef unsigned short u16;
typedef unsigned int u32;
typedef __attribute__((ext_vector_type(8))) __bf16 bf16x8;
typedef __attribute__((ext_vector_type(4))) float f32x4;
typedef __attribute__((ext_vector_type(4))) unsigned short u16x4;
typedef __attribute__((ext_vector_type(8))) unsigned short u16x8;

__device__ __forceinline__ u16 f2bf(float f){
  u32 u = __float_as_uint(f);
  u32 r = (u + 0x7FFFu + ((u >> 16) & 1u)) >> 16;
  return (u16)r;
}
__device__ __forceinline__ float bf2f(u16 h){
  return __uint_as_float(((u32)h) << 16);
}
__device__ __forceinline__ void gload_lds16(const void* g, void* l){
  __builtin_amdgcn_global_load_lds((const __attribute__((address_space(1))) void*)g,
                                   (__attribute__((address_space(3))) void*)l, 16, 0, 0);
}

// ================= 256x256 8-phase GEMM (T2+T3+T4+T5) — attempt 3 =================
// Identical schedule to R3 (race-free, refcheck'd) EXCEPT: only ONE
// sched_barrier(0), after lgkmcnt(0) (rule #18). R3 had three per phase ->
// m141 failure mode (order-pinning defeats compiler scheduling, ~510-533 TF).
// 512 thr = 8 waves (2M x 4N), per-wave 128x64 out = acc[8][4]. BK=64, 2 k-halves.
// LDS 128KB: buf{0,1} x { A[256][kh][32], B[256][kh][32] }, 16KB half-slabs.
// Half-tile stream h: type h&3: 0=B_k0 1=A_k0 2=B_k1 3=A_k1, K-tile h>>2, buf (h>>2)&1.
// Stage lag 6 half-tiles; vmcnt(6) only at phases 4/8; vmcnt(0) before last K-tile.
// LDS XOR swizzle both-sides: phys chunk = logical ^ ((row>>1)&3) (conflicts=0, R3).
// EPI: 0=bf16 out; 1=f32 resid+acc+rowv; 2=bf16 gelu(acc+bias); 3=f32 +=acc+bias

#define MM4(FM, AV) \
  acc[FM][0] = __builtin_amdgcn_mfma_f32_16x16x32_bf16(AV, b0, acc[FM][0],0,0,0); \
  acc[FM][1] = __builtin_amdgcn_mfma_f32_16x16x32_bf16(AV, b1, acc[FM][1],0,0,0); \
  acc[FM][2] = __builtin_amdgcn_mfma_f32_16x16x32_bf16(AV, b2, acc[FM][2],0,0,0); \
  acc[FM][3] = __builtin_amdgcn_mfma_f32_16x16x32_bf16(AV, b3, acc[FM][3],0,0,0);

#define STAGE256(H2) do { if ((H2) < Htot){                                  \
  const int kt_ = (H2)>>2, ty_ = (H2)&3;                                     \
  const int kh_ = ty_>>1; const int isA_ = ty_&1;                            \
  const size_t ko_ = (size_t)kt_*64 + (size_t)kh_*32;                        \
  char* ld_ = ldsc + ((kt_&1)<<16) + ((isA_^1)<<15) + (kh_<<14) + tid*16;    \
  const u16* g0_ = (isA_ ? Ap + Ab0 : Bp + Bb0) + ko_;                       \
  const u16* g1_ = (isA_ ? Ap + Ab1 : Bp + Bb1) + ko_;                       \
  gload_lds16(g0_, ld_);                                                     \
  gload_lds16(g1_, ld_ + 8192);                                              \
}} while(0)

#define PHASE(BUFB, KHB, FMQ, LOADB, VMN) do {                               \
  const u16* pa_ = ldsu + (((BUFB)+(KHB))>>1) + aoffA;                       \
  bf16x8 a0_ = *(const bf16x8*)(pa_ + ((FMQ)*4+0)*512);                      \
  bf16x8 a1_ = *(const bf16x8*)(pa_ + ((FMQ)*4+1)*512);                      \
  bf16x8 a2_ = *(const bf16x8*)(pa_ + ((FMQ)*4+2)*512);                      \
  bf16x8 a3_ = *(const bf16x8*)(pa_ + ((FMQ)*4+3)*512);                      \
  if (LOADB){                                                                \
    const u16* pb_ = ldsu + (((BUFB)+32768+(KHB))>>1) + boffB;               \
    b0 = *(const bf16x8*)(pb_ + 0*512);                                      \
    b1 = *(const bf16x8*)(pb_ + 1*512);                                      \
    b2 = *(const bf16x8*)(pb_ + 2*512);                                      \
    b3 = *(const bf16x8*)(pb_ + 3*512);                                      \
  }                                                                          \
  STAGE256(hh); hh++;                                                        \
  __builtin_amdgcn_s_barrier();                                              \
  asm volatile("s_waitcnt lgkmcnt(0)" ::: "memory");                         \
  __builtin_amdgcn_sched_barrier(0);                                         \
  __builtin_amdgcn_s_setprio(1);                                             \
  MM4((FMQ)*4+0, a0_)                                                        \
  MM4((FMQ)*4+1, a1_)                                                        \
  MM4((FMQ)*4+2, a2_)                                                        \
  MM4((FMQ)*4+3, a3_)                                                        \
  __builtin_amdgcn_s_setprio(0);                                             \
  if ((VMN) == 6) { asm volatile("s_waitcnt vmcnt(6)" ::: "memory"); }       \
  else if ((VMN) == 0) { asm volatile("s_waitcnt vmcnt(0)" ::: "memory"); }  \
  __builtin_amdgcn_s_barrier();                                              \
} while(0)

template<int EPI>
__global__ __launch_bounds__(512, 2) void gemm256(
    const u16* __restrict__ Ap, const u16* __restrict__ Bp,
    int K, int N, int NBN,
    void* __restrict__ outp,
    const float* __restrict__ resid,
    const float* __restrict__ rowv,
    const float* __restrict__ bias)
{
  __shared__ __align__(16) char ldsraw[131072];
  char* ldsc = ldsraw;
  const u16* ldsu = (const u16*)ldsraw;

  const int tid = threadIdx.x;
  const int wid = tid >> 6, lane = tid & 63;
  const int wr = wid >> 2, wc = wid & 3;
  const int l15 = lane & 15;

  // block swizzle: XCD chunk (nwg%8==0), bn-fast within chunk
  const int nwg = gridDim.x;
  int wg = blockIdx.x;
  wg = (wg & 7) * (nwg >> 3) + (wg >> 3);
  const int bm = (wg / NBN) * 256;
  const int bn = (wg % NBN) * 256;

  f32x4 acc[8][4];
#pragma unroll
  for (int i=0;i<8;i++)
#pragma unroll
    for (int j=0;j<4;j++) acc[i][j] = (f32x4){0.f,0.f,0.f,0.f};

  // staging: slot tid -> row tid>>2, phys chunk tid&3; logical chunk pre-swizzled
  const int r0s = tid >> 2, c0s = (tid & 3) ^ ((tid >> 3) & 3);
  const size_t Ab0 = (size_t)(bm + r0s)*K       + (size_t)c0s*8;
  const size_t Ab1 = (size_t)(bm + 128 + r0s)*K + (size_t)c0s*8;
  const size_t Bb0 = (size_t)(bn + r0s)*K       + (size_t)c0s*8;
  const size_t Bb1 = (size_t)(bn + 128 + r0s)*K + (size_t)c0s*8;

  // fragment read offsets (u16 units within a kh slab), swizzled chunk
  const int physcb = ((lane >> 4) << 4) ^ (((l15 >> 1) & 3) << 4);
  const int aoffA = (wr*128 + l15)*32 + (physcb >> 1);
  const int boffB = (wc*64  + l15)*32 + (physcb >> 1);

  const int T = K >> 6;
  const int Htot = T*4;
  bf16x8 b0, b1, b2, b3;

  // prologue: stage h=0..6, land K-tile 0
  int hh = 0;
  STAGE256(0); STAGE256(1); STAGE256(2); STAGE256(3);
  asm volatile("s_waitcnt vmcnt(4)" ::: "memory");
  STAGE256(4); STAGE256(5); STAGE256(6);
  asm volatile("s_waitcnt vmcnt(6)" ::: "memory");
  __builtin_amdgcn_s_barrier();
  hh = 7;

  for (int kt = 0; kt < T; kt += 2){
    const int vm4 = (kt+1 == T-1) ? 0 : 6;
    const int vm8 = (kt+2 >= T) ? -1 : 6;
    PHASE(0,     0,     0, 1, -1);
    PHASE(0,     0,     1, 0, -1);
    PHASE(0,     16384, 0, 1, -1);
    PHASE(0,     16384, 1, 0, vm4);
    PHASE(65536, 0,     0, 1, -1);
    PHASE(65536, 0,     1, 0, -1);
    PHASE(65536, 16384, 0, 1, -1);
    PHASE(65536, 16384, 1, 0, vm8);
  }

  // epilogue: C/D layout col=lane&15, row=(lane>>4)*4+r (verified m89)
  const int col0 = bn + wc*64 + l15;
  const int row0 = bm + wr*128 + ((lane >> 4) << 2);
#pragma unroll
  for (int fm=0; fm<8; fm++){
#pragma unroll
    for (int fn=0; fn<4; fn++){
#pragma unroll
      for (int r2=0; r2<4; r2++){
        const int row = row0 + fm*16 + r2;
        const int cj  = col0 + fn*16;
        const size_t o = (size_t)row*N + cj;
        const float va = acc[fm][fn][r2];
        if constexpr (EPI == 0){
          ((u16*)outp)[o] = f2bf(va);
        } else if constexpr (EPI == 1){
          const float rs = __builtin_nontemporal_load(resid + o);
          ((float*)outp)[o] = rs + va + rowv[(row >> 12)*N + cj];
        } else if constexpr (EPI == 2){
          const float z = va + bias[cj];
          ((u16*)outp)[o] = f2bf(0.5f*z*(1.0f + erff(z*0.70710678f)));
        } else {
          float* po = (float*)outp + o;
          const float prev = __builtin_nontemporal_load(po);
          *po = prev + va + bias[cj];
        }
      }
    }
  }
}

// ---------------- LayerNorm over last dim (768): wave-per-row, float4 ----------------
__device__ __forceinline__ void ln_row(const float* __restrict__ p,
    const float* __restrict__ gam, const float* __restrict__ bet,
    u16* __restrict__ op, int lane)
{
  float4 v0 = *reinterpret_cast<const float4*>(p + lane*4);
  float4 v1 = *reinterpret_cast<const float4*>(p + lane*4 + 256);
  float4 v2 = *reinterpret_cast<const float4*>(p + lane*4 + 512);
  float s  = v0.x+v0.y+v0.z+v0.w + v1.x+v1.y+v1.z+v1.w + v2.x+v2.y+v2.z+v2.w;
  float sq = v0.x*v0.x+v0.y*v0.y+v0.z*v0.z+v0.w*v0.w
           + v1.x*v1.x+v1.y*v1.y+v1.z*v1.z+v1.w*v1.w
           + v2.x*v2.x+v2.y*v2.y+v2.z*v2.z+v2.w*v2.w;
#pragma unroll
  for (int o=32;o>0;o>>=1){ s += __shfl_xor(s,o); sq += __shfl_xor(sq,o); }
  const float mu = s * (1.f/C_);
  const float rs = rsqrtf(sq*(1.f/C_) - mu*mu + 1e-5f);
  float4 g0 = *reinterpret_cast<const float4*>(gam + lane*4);
  float4 g1 = *reinterpret_cast<const float4*>(gam + lane*4 + 256);
  float4 g2 = *reinterpret_cast<const float4*>(gam + lane*4 + 512);
  float4 b0 = *reinterpret_cast<const float4*>(bet + lane*4);
  float4 b1 = *reinterpret_cast<const float4*>(bet + lane*4 + 256);
  float4 b2 = *reinterpret_cast<const float4*>(bet + lane*4 + 512);
  u16x4 o0, o1, o2;
  o0[0]=f2bf((v0.x-mu)*rs*g0.x+b0.x); o0[1]=f2bf((v0.y-mu)*rs*g0.y+b0.y);
  o0[2]=f2bf((v0.z-mu)*rs*g0.z+b0.z); o0[3]=f2bf((v0.w-mu)*rs*g0.w+b0.w);
  o1[0]=f2bf((v1.x-mu)*rs*g1.x+b1.x); o1[1]=f2bf((v1.y-mu)*rs*g1.y+b1.y);
  o1[2]=f2bf((v1.z-mu)*rs*g1.z+b1.z); o1[3]=f2bf((v1.w-mu)*rs*g1.w+b1.w);
  o2[0]=f2bf((v2.x-mu)*rs*g2.x+b2.x); o2[1]=f2bf((v2.y-mu)*rs*g2.y+b2.y);
  o2[2]=f2bf((v2.z-mu)*rs*g2.z+b2.z); o2[3]=f2bf((v2.w-mu)*rs*g2.w+b2.w);
  *reinterpret_cast<u16x4*>(op + lane*4)       = o0;
  *reinterpret_cast<u16x4*>(op + lane*4 + 256) = o1;
  *reinterpret_cast<u16x4*>(op + lane*4 + 512) = o2;
}

__global__ __launch_bounds__(256) void ln_fwd(const float* __restrict__ in,
    const float* __restrict__ gam, const float* __restrict__ bet,
    u16* __restrict__ out)
{
  const int row  = blockIdx.x*4 + (threadIdx.x >> 6);
  const int lane = threadIdx.x & 63;
  ln_row(in + (size_t)row*C_, gam, bet, out + (size_t)row*C_, lane);
}

// LN1 for x and y; ALSO emits raw bf16 cast of the input (saves the cvt pass)
__global__ __launch_bounds__(256) void ln_fwd2(const float* __restrict__ inx,
    const float* __restrict__ iny, const float* __restrict__ gam,
    const float* __restrict__ bet, u16* __restrict__ outx, u16* __restrict__ outy,
    u16* __restrict__ outxb, u16* __restrict__ outyb)
{
  const int row  = blockIdx.x*4 + (threadIdx.x >> 6);
  const int lane = threadIdx.x & 63;
  const float* in = blockIdx.y ? iny : inx;
  u16* out  = blockIdx.y ? outy  : outx;
  u16* outb = blockIdx.y ? outyb : outxb;
  const float* p = in + (size_t)row*C_;
  u16* op  = out  + (size_t)row*C_;
  u16* opb = outb + (size_t)row*C_;

  float4 v0 = *reinterpret_cast<const float4*>(p + lane*4);
  float4 v1 = *reinterpret_cast<const float4*>(p + lane*4 + 256);
  float4 v2 = *reinterpret_cast<const float4*>(p + lane*4 + 512);
  u16x4 rb;
  rb[0]=f2bf(v0.x); rb[1]=f2bf(v0.y); rb[2]=f2bf(v0.z); rb[3]=f2bf(v0.w);
  *reinterpret_cast<u16x4*>(opb + lane*4) = rb;
  rb[0]=f2bf(v1.x); rb[1]=f2bf(v1.y); rb[2]=f2bf(v1.z); rb[3]=f2bf(v1.w);
  *reinterpret_cast<u16x4*>(opb + lane*4 + 256) = rb;
  rb[0]=f2bf(v2.x); rb[1]=f2bf(v2.y); rb[2]=f2bf(v2.z); rb[3]=f2bf(v2.w);
  *reinterpret_cast<u16x4*>(opb + lane*4 + 512) = rb;

  float s  = v0.x+v0.y+v0.z+v0.w + v1.x+v1.y+v1.z+v1.w + v2.x+v2.y+v2.z+v2.w;
  float sq = v0.x*v0.x+v0.y*v0.y+v0.z*v0.z+v0.w*v0.w
           + v1.x*v1.x+v1.y*v1.y+v1.z*v1.z+v1.w*v1.w
           + v2.x*v2.x+v2.y*v2.y+v2.z*v2.z+v2.w*v2.w;
#pragma unroll
  for (int o=32;o>0;o>>=1){ s += __shfl_xor(s,o); sq += __shfl_xor(sq,o); }
  const float mu = s * (1.f/C_);
  const float rs = rsqrtf(sq*(1.f/C_) - mu*mu + 1e-5f);
  float4 g0 = *reinterpret_cast<const float4*>(gam + lane*4);
  float4 g1 = *reinterpret_cast<const float4*>(gam + lane*4 + 256);
  float4 g2 = *reinterpret_cast<const float4*>(gam + lane*4 + 512);
  float4 b0 = *reinterpret_cast<const float4*>(bet + lane*4);
  float4 b1 = *reinterpret_cast<const float4*>(bet + lane*4 + 256);
  float4 b2 = *reinterpret_cast<const float4*>(bet + lane*4 + 512);
  u16x4 o0, o1, o2;
  o0[0]=f2bf((v0.x-mu)*rs*g0.x+b0.x); o0[1]=f2bf((v0.y-mu)*rs*g0.y+b0.y);
  o0[2]=f2bf((v0.z-mu)*rs*g0.z+b0.z); o0[3]=f2bf((v0.w-mu)*rs*g0.w+b0.w);
  o1[0]=f2bf((v1.x-mu)*rs*g1.x+b1.x); o1[1]=f2bf((v1.y-mu)*rs*g1.y+b1.y);
  o1[2]=f2bf((v1.z-mu)*rs*g1.z+b1.z); o1[3]=f2bf((v1.w-mu)*rs*g1.w+b1.w);
  o2[0]=f2bf((v2.x-mu)*rs*g2.x+b2.x); o2[1]=f2bf((v2.y-mu)*rs*g2.y+b2.y);
  o2[2]=f2bf((v2.z-mu)*rs*g2.z+b2.z); o2[3]=f2bf((v2.w-mu)*rs*g2.w+b2.w);
  *reinterpret_cast<u16x4*>(op + lane*4)       = o0;
  *reinterpret_cast<u16x4*>(op + lane*4 + 256) = o1;
  *reinterpret_cast<u16x4*>(op + lane*4 + 512) = o2;
}

// ---------------- all 7 weight transposes in one launch ----------------
__device__ __forceinline__ void tr_tile(const float* __restrict__ in,
    u16* __restrict__ outp, int R, int Cc, int t)
{
  __shared__ float tile[32][33];
  const int tilesx = Cc >> 5;
  const int c0 = (t % tilesx)*32, r0 = (t / tilesx)*32;
  const int tx = threadIdx.x & 31, ty = threadIdx.x >> 5;
#pragma unroll
  for (int i=0;i<32;i+=8)
    tile[ty+i][tx] = in[(size_t)(r0+ty+i)*Cc + c0+tx];
  __syncthreads();
#pragma unroll
  for (int i=0;i<32;i+=8)
    outp[(size_t)(c0+ty+i)*R + r0+tx] = f2bf(tile[tx][ty+i]);
}

__global__ __launch_bounds__(256) void transpose_all(
    const float* Wk, const float* Wpx, const float* Wpy,
    const float* f1x, const float* f2x, const float* f1y, const float* f2y,
    u16* WkT, u16* WpxT, u16* WpyT, u16* f1xT, u16* f2xT, u16* f1yT, u16* f2yT)
{
  int t = blockIdx.x;
  if (t < 1728){
    const int m = t / 576; t -= m*576;
    const float* in = (m==0)?Wk:((m==1)?Wpx:Wpy);
    u16* o = (m==0)?WkT:((m==1)?WpxT:WpyT);
    tr_tile(in, o, C_, C_, t);
  } else {
    t -= 1728;
    const int m = t / 2304; t -= m*2304;
    if (m==0)      tr_tile(f1x, f1xT, C_, H_, t);
    else if (m==1) tr_tile(f2x, f2xT, H_, C_, t);
    else if (m==2) tr_tile(f1y, f1yT, C_, H_, t);
    else           tr_tile(f2y, f2yT, H_, C_, t);
  }
}

// ---------------- masked pooling partials of yn (+ mask partial) ----------------
__global__ __launch_bounds__(256) void pool_partial(const u16* __restrict__ q,
    const float* __restrict__ mask, float* __restrict__ pm, float* __restrict__ pa,
    float* __restrict__ mpart)
{
  const int c = blockIdx.x*256 + threadIdx.x;
  const int b = blockIdx.y, z = blockIdx.z;
  const int n0 = z*(N_/NSPLIT);
  const u16* qp = q + ((size_t)b*N_ + n0)*C_ + c;
  const float* mp = mask + (size_t)b*N_ + n0;
  float am=0.f, aa=0.f, ms=0.f;
  for (int n=0;n<N_/NSPLIT;n++){
    float v = bf2f(qp[(size_t)n*C_]);
    float m = mp[n];
    am += v*m; aa += v; ms += m;
  }
  const size_t o = ((size_t)z*B_ + b)*C_ + c;
  pm[o]=am; pa[o]=aa;
  if (blockIdx.x==0 && threadIdx.x==0) mpart[z*B_+b] = ms;
}

// ---------------- proto_fused: pool_final + (fg,bg)=pooled@Wq + norms ----------------
__global__ __launch_bounds__(256) void proto_fused(const float* __restrict__ pm,
    const float* __restrict__ pa, const float* __restrict__ mpart,
    const float* __restrict__ Wq,
    float* __restrict__ fg, float* __restrict__ bg,
    float* __restrict__ fgn, float* __restrict__ bgn)
{
  __shared__ float fin[C_], bin[C_];
  __shared__ float red[8];
  const int b = blockIdx.x, tid = threadIdx.x;
  float msum_b = 0.f;
#pragma unroll
  for (int z=0;z<NSPLIT;z++) msum_b += mpart[z*B_+b];
  for (int c=tid;c<C_;c+=256){
    float sm=0.f, sa=0.f;
#pragma unroll
    for (int z=0;z<NSPLIT;z++){ size_t o=((size_t)z*B_+b)*C_+c; sm+=pm[o]; sa+=pa[o]; }
    fin[c] = sm/(msum_b + 5e-4f);
    bin[c] = (sa - sm)/((float)N_ - msum_b + 5e-4f);
  }
  __syncthreads();
  const int j0 = tid, j1 = tid+256, j2 = tid+512;
  float f0=0,f1=0,f2=0,g0=0,g1=0,g2=0;
  for (int c=0;c<C_;c++){
    const float* w = Wq + (size_t)c*C_;
    float fc = fin[c], bc = bin[c];
    float w0=w[j0], w1=w[j1], w2=w[j2];
    f0 += fc*w0; f1 += fc*w1; f2 += fc*w2;
    g0 += bc*w0; g1 += bc*w1; g2 += bc*w2;
  }
  fg[b*C_+j0]=f0; fg[b*C_+j1]=f1; fg[b*C_+j2]=f2;
  bg[b*C_+j0]=g0; bg[b*C_+j1]=g1; bg[b*C_+j2]=g2;
  float sf = f0*f0+f1*f1+f2*f2, sb = g0*g0+g1*g1+g2*g2;
#pragma unroll
  for (int o=32;o>0;o>>=1){ sf+=__shfl_down(sf,o); sb+=__shfl_down(sb,o); }
  if ((tid&63)==0){ red[tid>>6]=sf; red[4+(tid>>6)]=sb; }
  __syncthreads();
  if (tid==0){
    fgn[b]=sqrtf(red[0]+red[1]+red[2]+red[3]);
    bgn[b]=sqrtf(red[4]+red[5]+red[6]+red[7]);
  }
}

// ---------------- cosine scores: wave-per-token ----------------
__global__ __launch_bounds__(256) void score_kernel(const u16* __restrict__ k,
    const float* __restrict__ fg, const float* __restrict__ bg,
    const float* __restrict__ fgn, const float* __restrict__ bgn,
    float* __restrict__ fg_s, float* __restrict__ bg_s)
{
  const int t = blockIdx.x*4 + (threadIdx.x >> 6);
  const int lane = threadIdx.x & 63;
  const int b = t >> 12;
  const u16* kp = k + (size_t)t*C_;
  u16x8 k8 = *reinterpret_cast<const u16x8*>(kp + lane*8);
  u16x4 k4 = *reinterpret_cast<const u16x4*>(kp + 512 + lane*4);
  const float* fgp = fg + b*C_;
  const float* bgp = bg + b*C_;
  float4 fa = *reinterpret_cast<const float4*>(fgp + lane*8);
  float4 fb = *reinterpret_cast<const float4*>(fgp + lane*8 + 4);
  float4 fc = *reinterpret_cast<const float4*>(fgp + 512 + lane*4);
  float4 ba = *reinterpret_cast<const float4*>(bgp + lane*8);
  float4 bb = *reinterpret_cast<const float4*>(bgp + lane*8 + 4);
  float4 bc = *reinterpret_cast<const float4*>(bgp + 512 + lane*4);
  float kv[12];
#pragma unroll
  for (int i=0;i<8;i++) kv[i] = bf2f(k8[i]);
#pragma unroll
  for (int i=0;i<4;i++) kv[8+i] = bf2f(k4[i]);
  float df = kv[0]*fa.x+kv[1]*fa.y+kv[2]*fa.z+kv[3]*fa.w
           + kv[4]*fb.x+kv[5]*fb.y+kv[6]*fb.z+kv[7]*fb.w
           + kv[8]*fc.x+kv[9]*fc.y+kv[10]*fc.z+kv[11]*fc.w;
  float db = kv[0]*ba.x+kv[1]*ba.y+kv[2]*ba.z+kv[3]*ba.w
           + kv[4]*bb.x+kv[5]*bb.y+kv[6]*bb.z+kv[7]*bb.w
           + kv[8]*bc.x+kv[9]*bc.y+kv[10]*bc.z+kv[11]*bc.w;
  float kk=0.f;
#pragma unroll
  for (int i=0;i<12;i++) kk += kv[i]*kv[i];
#pragma unroll
  for (int o=32;o>0;o>>=1){
    df+=__shfl_xor(df,o); db+=__shfl_xor(db,o); kk+=__shfl_xor(kk,o);
  }
  if (lane==0){
    const float kn = sqrtf(kk);
    fg_s[t] = df/(kn*fgn[b]+1e-7f);
    bg_s[t] = db/(kn*bgn[b]+1e-7f);
  }
}

__global__ __launch_bounds__(256) void minmax_kernel(const float* __restrict__ fg_s,
    const float* __restrict__ bg_s, float* __restrict__ mm)
{
  __shared__ float sm[16];
  const int b = blockIdx.x;
  float mnf=1e30f, mxf=-1e30f, mnb=1e30f, mxb=-1e30f;
  for (int i=threadIdx.x;i<N_;i+=256){
    float a = fg_s[(size_t)b*N_+i]; mnf=fminf(mnf,a); mxf=fmaxf(mxf,a);
    float c = bg_s[(size_t)b*N_+i]; mnb=fminf(mnb,c); mxb=fmaxf(mxb,c);
  }
#pragma unroll
  for (int o=32;o>0;o>>=1){
    mnf=fminf(mnf,__shfl_down(mnf,o)); mxf=fmaxf(mxf,__shfl_down(mxf,o));
    mnb=fminf(mnb,__shfl_down(mnb,o)); mxb=fmaxf(mxb,__shfl_down(mxb,o));
  }
  const int wid = threadIdx.x>>6;
  if ((threadIdx.x&63)==0){ sm[wid]=mnf; sm[4+wid]=mxf; sm[8+wid]=mnb; sm[12+wid]=mxb; }
  __syncthreads();
  if (threadIdx.x==0){
    mm[b*4+0]=fminf(fminf(sm[0],sm[1]),fminf(sm[2],sm[3]));
    mm[b*4+1]=fmaxf(fmaxf(sm[4],sm[5]),fmaxf(sm[6],sm[7]));
    mm[b*4+2]=fminf(fminf(sm[8],sm[9]),fminf(sm[10],sm[11]));
    mm[b*4+3]=fmaxf(fmaxf(sm[12],sm[13]),fmaxf(sm[14],sm[15]));
  }
}

// scores -> pseudo out + exp weights + denom, one block per b (1024 thr)
__global__ __launch_bounds__(1024) void scorefin_fused(const float* __restrict__ fg_s,
    const float* __restrict__ bg_s, const float* __restrict__ mm,
    float* __restrict__ pseudo, float* __restrict__ escr, float* __restrict__ denom)
{
  __shared__ float sm[16];
  const int b = blockIdx.x, tid = threadIdx.x;
  const float mnf=mm[b*4+0], mxf=mm[b*4+1], mnb=mm[b*4+2], mxb=mm[b*4+3];
  const float rf = 1.f/(mxf-mnf+1e-7f), rb = 1.f/(mxb-mnb+1e-7f);
  float ps = 0.f;
#pragma unroll
  for (int i=0;i<4;i++){
    const int t = tid + i*1024;
    const size_t o = (size_t)b*N_ + t;
    const float s = (fg_s[o]-mnf)*rf - (bg_s[o]-mnb)*rb;
    pseudo[o] = s;
    const float e = expf(s < 0.f ? s - 100.f : s);
    escr[o] = e;
    ps += e;
  }
#pragma unroll
  for (int o=32;o>0;o>>=1) ps += __shfl_down(ps,o);
  if ((tid&63)==0) sm[tid>>6]=ps;
  __syncthreads();
  if (tid==0){
    float s=0.f;
#pragma unroll
    for (int w=0;w<16;w++) s+=sm[w];
    denom[b]=s;
  }
}

// attn-pool partials of xn
__global__ __launch_bounds__(256) void vpool_partial(const u16* __restrict__ xn,
    const float* __restrict__ e, float* __restrict__ pv)
{
  const int c = blockIdx.x*256 + threadIdx.x;
  const int b = blockIdx.y, z = blockIdx.z;
  const int n0 = z*(N_/NSPLIT);
  const u16* vp = xn + ((size_t)b*N_ + n0)*C_ + c;
  const float* ep = e + (size_t)b*N_ + n0;
  float acc=0.f;
  for (int n=0;n<N_/NSPLIT;n++) acc += bf2f(vp[(size_t)n*C_])*ep[n];
  pv[((size_t)z*B_+b)*C_+c] = acc;
}

// pro_fused: vpool_final + qp=vin@Wv + sim + pro + rowx/rowy = pro@Wp*B
__global__ __launch_bounds__(256) void pro_fused(const float* __restrict__ pv,
    const float* __restrict__ denom,
    const float* __restrict__ Wv, const float* __restrict__ Wpx,
    const float* __restrict__ Wpy,
    const float* __restrict__ fg, const float* __restrict__ fgn,
    float* __restrict__ rowx, float* __restrict__ rowy)
{
  __shared__ float vin[C_];
  __shared__ float red[8];
  __shared__ float simsh;
  const int b = blockIdx.x, tid = threadIdx.x;
  const float den = 1.f/denom[b];
  for (int c=tid;c<C_;c+=256){
    float s=0.f;
#pragma unroll
    for (int z=0;z<NSPLIT;z++) s += pv[((size_t)z*B_+b)*C_+c];
    vin[c] = s*den;
  }
  __syncthreads();
  const int j0 = tid, j1 = tid+256, j2 = tid+512;
  float q0=0,q1=0,q2=0;
  for (int c=0;c<C_;c++){
    const float* w = Wv + (size_t)c*C_;
    float vv = vin[c];
    q0 += vv*w[j0]; q1 += vv*w[j1]; q2 += vv*w[j2];
  }
  const float fg0 = fg[b*C_+j0], fg1 = fg[b*C_+j1], fg2 = fg[b*C_+j2];
  float d = q0*fg0 + q1*fg1 + q2*fg2;
  float qq = q0*q0 + q1*q1 + q2*q2;
#pragma unroll
  for (int o=32;o>0;o>>=1){ d+=__shfl_down(d,o); qq+=__shfl_down(qq,o); }
  if ((tid&63)==0){ red[tid>>6]=d; red[4+(tid>>6)]=qq; }
  __syncthreads();
  if (tid==0){
    float dd=red[0]+red[1]+red[2]+red[3], qs=red[4]+red[5]+red[6]+red[7];
    simsh = (dd/(sqrtf(qs)*fgn[b]+1e-7f)+1.f)*0.5f;
  }
  __syncthreads();
  const float sim = simsh;
  vin[j0] = sim*fg0 + (1.f-sim)*q0;
  vin[j1] = sim*fg1 + (1.f-sim)*q1;
  vin[j2] = sim*fg2 + (1.f-sim)*q2;
  __syncthreads();
  float rx0=0,rx1=0,rx2=0, ry0=0,ry1=0,ry2=0;
  for (int c=0;c<C_;c++){
    const float* wx = Wpx + (size_t)(C_+c)*C_;
    const float* wy = Wpy + (size_t)(C_+c)*C_;
    float pc = vin[c];
    rx0 += pc*wx[j0]; rx1 += pc*wx[j1]; rx2 += pc*wx[j2];
    ry0 += pc*wy[j0]; ry1 += pc*wy[j1]; ry2 += pc*wy[j2];
  }
  rowx[b*C_+j0]=rx0; rowx[b*C_+j1]=rx1; rowx[b*C_+j2]=rx2;
  rowy[b*C_+j0]=ry0; rowy[b*C_+j1]=ry1; rowy[b*C_+j2]=ry2;
}

// ---------------- launcher ----------------
extern "C" void kernel_launch(void* const* d_in, const int* in_sizes, int n_in,
                              void* d_out, int out_size, void* d_ws, size_t ws_size,
                              hipStream_t stream)
{
  const float* x     = (const float*)d_in[0];
  const float* y     = (const float*)d_in[1];
  const float* mask  = (const float*)d_in[2];
  const float* ln1_g = (const float*)d_in[5];
  const float* ln1_b = (const float*)d_in[6];
  const float* Wq    = (const float*)d_in[7];
  const float* Wk    = (const float*)d_in[8];
  const float* Wv    = (const float*)d_in[9];
  const float* Wpx   = (const float*)d_in[10];
  const float* Wpy   = (const float*)d_in[11];
  const float* ln2_g = (const float*)d_in[12];
  const float* ln2_b = (const float*)d_in[13];
  const float* fx1_w = (const float*)d_in[14];
  const float* fx1_b = (const float*)d_in[15];
  const float* fx2_w = (const float*)d_in[16];
  const float* fx2_b = (const float*)d_in[17];
  const float* fy1_w = (const float*)d_in[18];
  const float* fy1_b = (const float*)d_in[19];
  const float* fy2_w = (const float*)d_in[20];
  const float* fy2_b = (const float*)d_in[21];

  float* out    = (float*)d_out;
  float* out_xo = out;
  float* out_yo = out + (size_t)M_*C_;
  float* out_ps = out + 2*(size_t)M_*C_;

  char* ws = (char*)d_ws;
  const size_t ACT = (size_t)M_*C_;
  u16* R0  = (u16*)ws;
  u16* xnb = R0;                           // slot0: xn
  u16* ynb = R0 + ACT;                     // slot1: yn
  u16* kb  = R0 + 2*ACT;                   // slot2: k
  u16* xb  = R0 + 3*ACT;                   // slot3: x bf16 (dead after proj-x)
  u16* yb  = (u16*)(ws + 4*ACT*2);         // slot4: y bf16 (dead after proj-y)
  u16* qb  = yb;                           // slot4 reused: ln2 out
  u16* hid = R0;                           // MLP hidden aliases slots 0-3
  u16* wp  = (u16*)(ws + 5*ACT*2);
  u16* WkT  = wp;
  u16* WpxT = wp + 1*589824;
  u16* WpyT = wp + 2*589824;
  u16* fx1T = wp + 3*589824;
  u16* fx2T = fx1T + 2359296;
  u16* fy1T = fx2T + 2359296;
  u16* fy2T = fy1T + 2359296;
  float* st   = (float*)(ws + 5*ACT*2 + (size_t)(3*589824 + 4*2359296)*2);
  float* fgn  = st + 8;
  float* bgn  = st + 16;
  float* denom= st + 24;
  float* mm   = st + 32;
  float* fg   = st + 64;
  float* bg   = st + 6208;
  float* rowx = st + 24640;
  float* rowy = st + 30784;
  float* fg_s = st + 37056;
  float* bg_s = st + 69824;
  float* escr = st + 102592;
  float* pm   = st + 135360;
  float* pa   = st + 233664;
  float* pv   = st + 331968;
  float* mpart= st + 430272;

  dim3 tb(256);
  dim3 tg(512);

  // --- weights -> bf16 [N,K] + LN1(x,y) (also emits raw bf16 x,y) ---
  transpose_all<<<dim3(10944),tb,0,stream>>>(Wk,Wpx,Wpy,fx1_w,fx2_w,fy1_w,fy2_w,
                                             WkT,WpxT,WpyT,fx1T,fx2T,fy1T,fy2T);
  ln_fwd2<<<dim3(M_/4,2),tb,0,stream>>>(x, y, ln1_g, ln1_b, xnb, ynb, xb, yb);

  // --- k GEMM (q,v eliminated by pooling linearity) ---
  gemm256<0><<<dim3(128*3),tg,0,stream>>>(xnb, WkT, C_, C_, 3, kb, nullptr,nullptr,nullptr);

  // --- prototypes fg,bg (f32 path) ---
  pool_partial<<<dim3(3,B_,NSPLIT),tb,0,stream>>>(ynb, mask, pm, pa, mpart);
  proto_fused<<<B_,tb,0,stream>>>(pm, pa, mpart, Wq, fg, bg, fgn, bgn);

  // --- cosine scores + softmax weights ---
  score_kernel<<<M_/4,tb,0,stream>>>(kb, fg, bg, fgn, bgn, fg_s, bg_s);
  minmax_kernel<<<B_,tb,0,stream>>>(fg_s, bg_s, mm);
  scorefin_fused<<<B_,dim3(1024),0,stream>>>(fg_s, bg_s, mm, out_ps, escr, denom);

  // --- query_pro path + pro + row-vectors ---
  vpool_partial<<<dim3(3,B_,NSPLIT),tb,0,stream>>>(xnb, escr, pv);
  pro_fused<<<B_,tb,0,stream>>>(pv, denom, Wv, Wpx, Wpy, fg, fgn, rowx, rowy);

  // --- projection GEMMs: out = resid + act@WpA + pro@WpB ---
  gemm256<1><<<dim3(128*3),tg,0,stream>>>(xb, WpxT, C_, C_, 3, out_xo, x, rowx, nullptr);
  gemm256<1><<<dim3(128*3),tg,0,stream>>>(yb, WpyT, C_, C_, 3, out_yo, y, rowy, nullptr);

  // --- x MLP ---
  ln_fwd<<<M_/4,tb,0,stream>>>(out_xo, ln2_g, ln2_b, qb);
  gemm256<2><<<dim3(128*12),tg,0,stream>>>(qb, fx1T, C_, H_, 12, hid, nullptr,nullptr, fx1_b);
  gemm256<3><<<dim3(128*3),tg,0,stream>>>(hid, fx2T, H_, C_, 3, out_xo, nullptr,nullptr, fx2_b);

  // --- y MLP ---
  ln_fwd<<<M_/4,tb,0,stream>>>(out_yo, ln2_g, ln2_b, qb);
  gemm256<2><<<dim3(128*12),tg,0,stream>>>(qb, fy1T, C_, H_, 12, hid, nullptr,nullptr, fy1_b);
  gemm256<3><<<dim3(128*3),tg,0,stream>>>(hid, fy2T, H_, C_, 3, out_yo, nullptr,nullptr, fy2_b);
}

// Round 11
// 1568.489 us; speedup vs baseline: 1.1182x; 1.1182x over previous
//
#include <hip/hip_runtime.h>
#include <math.h>

#define B_ 8
#define N_ 4096
#define C_ 768
#define H_ 3072
#define M_ (B_*N_)
#define NSPLIT 16

typedef unsigned short u16;
typedef unsigned int u32;
typedef __attribute__((ext_vector_type(8))) __bf16 bf16x8;
typedef __attribute__((ext_vector_type(4))) float f32x4;
typedef __attribute__((ext_vector_type(4))) unsigned short u16x4;
typedef __attribute__((ext_vector_type(8))) unsigned short u16x8;

__device__ __forceinline__ u16 f2bf(float f){
  u32 u = __float_as_uint(f);
  u32 r = (u + 0x7FFFu + ((u >> 16) & 1u)) >> 16;
  return (u16)r;
}
__device__ __forceinline__ float bf2f(u16 h){
  return __uint_as_float(((u32)h) << 16);
}
__device__ __forceinline__ void gload_lds16(const void* g, void* l){
  __builtin_amdgcn_global_load_lds((const __attribute__((address_space(1))) void*)g,
                                   (__attribute__((address_space(3))) void*)l, 16, 0, 0);
}

// ---------------- GEMM: C[M,N] = A[M,K](bf16) * BT[N,K](bf16)^T ----------------
// R9 kernel (best known: 663 TF at the 2-phase structural plateau).
// 256x128 tile, 512 thr = 8 waves (4M x 2N) [AM-GM-optimal LDS read tiling],
// TRIPLE-buffered LDS, 2-deep prefetch, counted s_waitcnt vmcnt(3) (T4),
// K-loop unrolled x3 (literal buffer indices; VALU 70->11%, R9),
// LDS XOR swizzle both-sides (conflicts = 0, R6). Stores CACHED (R7 lesson:
// nt stores -> partial-line writeback). nt loads on read-once f32.
// B2=1: batched pair mode — blockIdx.y selects stream {A,BT,out,resid,rowv}
// (used for the two projection GEMMs: 2x768 blocks -> 1x1536, kills the
// 1.5-round scheduling tail on the 512-slot machine).
// EPI: 0=bf16 out; 1=f32 resid+acc+rowv; 2=bf16 gelu(acc+bias); 3=f32 +=acc+bias
template<int EPI, int GM, int B2>
__global__ __launch_bounds__(512, 4) void gemm_bf16(
    const u16* __restrict__ A, const u16* __restrict__ BT,
    int K, int N, int NBN,
    void* __restrict__ outp,
    const float* __restrict__ resid,
    const float* __restrict__ rowv,
    const float* __restrict__ bias,
    const u16* A2, const u16* BT2, void* outp2,
    const float* resid2, const float* rowv2)
{
  __shared__ u16 lds[3][12288];
  const int tid = threadIdx.x;
  const int wid = tid >> 6, lane = tid & 63;

  if constexpr (B2){
    if (blockIdx.y){
      A = A2; BT = BT2; outp = outp2; resid = resid2; rowv = rowv2;
    }
  }

  // block swizzle: XCD chunk (nwg%8==0) + GM row-panel grouping
  const int nwg = gridDim.x;
  int wg = blockIdx.x;
  wg = (wg & 7) * (nwg >> 3) + (wg >> 3);
  const int GMN = GM * NBN;
  const int g = wg / GMN, r = wg % GMN;
  const int bm = (g*GM + (r % GM)) * 256;
  const int bn = (r / GM) * 128;

  const int wr = wid >> 1, wc = wid & 1;
  const int l15 = lane & 15;

  f32x4 acc[4][4];
#pragma unroll
  for (int i=0;i<4;i++)
#pragma unroll
    for (int j=0;j<4;j++) acc[i][j] = (f32x4){0.f,0.f,0.f,0.f};

  // staging: slot tid -> row tid>>2, phys chunk tid&3; logical chunk pre-swizzled
  const int srow = tid >> 2;
  const int lchq = (tid & 3) ^ ((tid >> 3) & 3);     // (tid&3) ^ ((srow>>1)&3)
  const u16* agp0 = A  + (size_t)(bm + srow)*K       + lchq*8;
  const u16* agp1 = A  + (size_t)(bm + 128 + srow)*K + lchq*8;
  const u16* bgp0 = BT + (size_t)(bn + srow)*K       + lchq*8;

  auto STAGE = [&](int bi){
    char* base = (char*)lds[bi] + wid*1024;   // wave-uniform base; HW adds lane*16
    gload_lds16(agp0, base);
    gload_lds16(agp1, base + 8192);
    gload_lds16(bgp0, base + 16384);
    agp0 += 32; agp1 += 32; bgp0 += 32;
  };

  // swizzled read offsets (u16 units); swz invariant across i (row step 16)
  const int arow = wr*64 + l15;
  const int brow = wc*64 + l15;
  const int aswz = (arow >> 1) & 3;
  const int bswz = (brow >> 1) & 3;
  const int aoff = arow*32 + (((lane>>4) ^ aswz) << 3);
  const int boff = 8192 + brow*32 + (((lane>>4) ^ bswz) << 3);

  const int nk = K >> 5;    // K=768 -> 24, K=3072 -> 96; both divisible by 3
  STAGE(0);
  STAGE(1);
  int kk2 = 0;

#define KSTEP(BI) do {                                                        \
    if (kk2 == nk-1){ asm volatile("s_waitcnt vmcnt(0)" ::: "memory"); }      \
    else            { asm volatile("s_waitcnt vmcnt(3)" ::: "memory"); }      \
    __builtin_amdgcn_s_barrier();                                             \
    __builtin_amdgcn_sched_barrier(0);                                        \
    if (kk2+2 < nk) STAGE((BI)==0 ? 2 : (BI)-1);  /* buf (kk+2)%3 */          \
    bf16x8 av[4], bv[4];                                                      \
    const u16* pa = &lds[BI][aoff];                                           \
    const u16* pb = &lds[BI][boff];                                           \
    _Pragma("unroll")                                                         \
    for (int i=0;i<4;i++){                                                    \
      av[i] = *reinterpret_cast<const bf16x8*>(pa + i*512);                   \
      bv[i] = *reinterpret_cast<const bf16x8*>(pb + i*512);                   \
    }                                                                         \
    _Pragma("unroll")                                                         \
    for (int i=0;i<4;i++)                                                     \
      _Pragma("unroll")                                                       \
      for (int j=0;j<4;j++)                                                   \
        acc[i][j] = __builtin_amdgcn_mfma_f32_16x16x32_bf16(av[i], bv[j],     \
                                                            acc[i][j],0,0,0); \
    kk2++;                                                                    \
  } while(0)

  for (int it = 0; it < nk/3; it++){
    KSTEP(0);
    KSTEP(1);
    KSTEP(2);
  }
#undef KSTEP

  // C/D layout (verified m89): col = lane&15, row = (lane>>4)*4 + r
  const int col0 = bn + wc*64 + l15;
  const int row0 = bm + wr*64 + ((lane >> 4) << 2);
#pragma unroll
  for (int i=0;i<4;i++){
#pragma unroll
    for (int j=0;j<4;j++){
#pragma unroll
      for (int r2=0;r2<4;r2++){
        const int row = row0 + i*16 + r2;
        const int cj  = col0 + j*16;
        const size_t o = (size_t)row*N + cj;
        const float va = acc[i][j][r2];
        if constexpr (EPI == 0){
          ((u16*)outp)[o] = f2bf(va);
        } else if constexpr (EPI == 1){
          const float rs = __builtin_nontemporal_load(resid + o);
          ((float*)outp)[o] = rs + va + rowv[(row >> 12)*N + cj];
        } else if constexpr (EPI == 2){
          const float z = va + bias[cj];
          ((u16*)outp)[o] = f2bf(0.5f*z*(1.0f + erff(z*0.70710678f)));
        } else {
          float* po = (float*)outp + o;
          const float prev = __builtin_nontemporal_load(po);
          *po = prev + va + bias[cj];
        }
      }
    }
  }
}

// ---------------- LayerNorm over last dim (768): wave-per-row, float4 ----------------
__device__ __forceinline__ void ln_row(const float* __restrict__ p,
    const float* __restrict__ gam, const float* __restrict__ bet,
    u16* __restrict__ op, int lane)
{
  float4 v0 = *reinterpret_cast<const float4*>(p + lane*4);
  float4 v1 = *reinterpret_cast<const float4*>(p + lane*4 + 256);
  float4 v2 = *reinterpret_cast<const float4*>(p + lane*4 + 512);
  float s  = v0.x+v0.y+v0.z+v0.w + v1.x+v1.y+v1.z+v1.w + v2.x+v2.y+v2.z+v2.w;
  float sq = v0.x*v0.x+v0.y*v0.y+v0.z*v0.z+v0.w*v0.w
           + v1.x*v1.x+v1.y*v1.y+v1.z*v1.z+v1.w*v1.w
           + v2.x*v2.x+v2.y*v2.y+v2.z*v2.z+v2.w*v2.w;
#pragma unroll
  for (int o=32;o>0;o>>=1){ s += __shfl_xor(s,o); sq += __shfl_xor(sq,o); }
  const float mu = s * (1.f/C_);
  const float rs = rsqrtf(sq*(1.f/C_) - mu*mu + 1e-5f);
  float4 g0 = *reinterpret_cast<const float4*>(gam + lane*4);
  float4 g1 = *reinterpret_cast<const float4*>(gam + lane*4 + 256);
  float4 g2 = *reinterpret_cast<const float4*>(gam + lane*4 + 512);
  float4 b0 = *reinterpret_cast<const float4*>(bet + lane*4);
  float4 b1 = *reinterpret_cast<const float4*>(bet + lane*4 + 256);
  float4 b2 = *reinterpret_cast<const float4*>(bet + lane*4 + 512);
  u16x4 o0, o1, o2;
  o0[0]=f2bf((v0.x-mu)*rs*g0.x+b0.x); o0[1]=f2bf((v0.y-mu)*rs*g0.y+b0.y);
  o0[2]=f2bf((v0.z-mu)*rs*g0.z+b0.z); o0[3]=f2bf((v0.w-mu)*rs*g0.w+b0.w);
  o1[0]=f2bf((v1.x-mu)*rs*g1.x+b1.x); o1[1]=f2bf((v1.y-mu)*rs*g1.y+b1.y);
  o1[2]=f2bf((v1.z-mu)*rs*g1.z+b1.z); o1[3]=f2bf((v1.w-mu)*rs*g1.w+b1.w);
  o2[0]=f2bf((v2.x-mu)*rs*g2.x+b2.x); o2[1]=f2bf((v2.y-mu)*rs*g2.y+b2.y);
  o2[2]=f2bf((v2.z-mu)*rs*g2.z+b2.z); o2[3]=f2bf((v2.w-mu)*rs*g2.w+b2.w);
  *reinterpret_cast<u16x4*>(op + lane*4)       = o0;
  *reinterpret_cast<u16x4*>(op + lane*4 + 256) = o1;
  *reinterpret_cast<u16x4*>(op + lane*4 + 512) = o2;
}

__global__ __launch_bounds__(256) void ln_fwd(const float* __restrict__ in,
    const float* __restrict__ gam, const float* __restrict__ bet,
    u16* __restrict__ out)
{
  const int row  = blockIdx.x*4 + (threadIdx.x >> 6);
  const int lane = threadIdx.x & 63;
  ln_row(in + (size_t)row*C_, gam, bet, out + (size_t)row*C_, lane);
}

// LN1 for x and y; ALSO emits raw bf16 cast of the input (saves the cvt pass)
__global__ __launch_bounds__(256) void ln_fwd2(const float* __restrict__ inx,
    const float* __restrict__ iny, const float* __restrict__ gam,
    const float* __restrict__ bet, u16* __restrict__ outx, u16* __restrict__ outy,
    u16* __restrict__ outxb, u16* __restrict__ outyb)
{
  const int row  = blockIdx.x*4 + (threadIdx.x >> 6);
  const int lane = threadIdx.x & 63;
  const float* in = blockIdx.y ? iny : inx;
  u16* out  = blockIdx.y ? outy  : outx;
  u16* outb = blockIdx.y ? outyb : outxb;
  const float* p = in + (size_t)row*C_;
  u16* op  = out  + (size_t)row*C_;
  u16* opb = outb + (size_t)row*C_;

  float4 v0 = *reinterpret_cast<const float4*>(p + lane*4);
  float4 v1 = *reinterpret_cast<const float4*>(p + lane*4 + 256);
  float4 v2 = *reinterpret_cast<const float4*>(p + lane*4 + 512);
  u16x4 rb;
  rb[0]=f2bf(v0.x); rb[1]=f2bf(v0.y); rb[2]=f2bf(v0.z); rb[3]=f2bf(v0.w);
  *reinterpret_cast<u16x4*>(opb + lane*4) = rb;
  rb[0]=f2bf(v1.x); rb[1]=f2bf(v1.y); rb[2]=f2bf(v1.z); rb[3]=f2bf(v1.w);
  *reinterpret_cast<u16x4*>(opb + lane*4 + 256) = rb;
  rb[0]=f2bf(v2.x); rb[1]=f2bf(v2.y); rb[2]=f2bf(v2.z); rb[3]=f2bf(v2.w);
  *reinterpret_cast<u16x4*>(opb + lane*4 + 512) = rb;

  float s  = v0.x+v0.y+v0.z+v0.w + v1.x+v1.y+v1.z+v1.w + v2.x+v2.y+v2.z+v2.w;
  float sq = v0.x*v0.x+v0.y*v0.y+v0.z*v0.z+v0.w*v0.w
           + v1.x*v1.x+v1.y*v1.y+v1.z*v1.z+v1.w*v1.w
           + v2.x*v2.x+v2.y*v2.y+v2.z*v2.z+v2.w*v2.w;
#pragma unroll
  for (int o=32;o>0;o>>=1){ s += __shfl_xor(s,o); sq += __shfl_xor(sq,o); }
  const float mu = s * (1.f/C_);
  const float rs = rsqrtf(sq*(1.f/C_) - mu*mu + 1e-5f);
  float4 g0 = *reinterpret_cast<const float4*>(gam + lane*4);
  float4 g1 = *reinterpret_cast<const float4*>(gam + lane*4 + 256);
  float4 g2 = *reinterpret_cast<const float4*>(gam + lane*4 + 512);
  float4 b0 = *reinterpret_cast<const float4*>(bet + lane*4);
  float4 b1 = *reinterpret_cast<const float4*>(bet + lane*4 + 256);
  float4 b2 = *reinterpret_cast<const float4*>(bet + lane*4 + 512);
  u16x4 o0, o1, o2;
  o0[0]=f2bf((v0.x-mu)*rs*g0.x+b0.x); o0[1]=f2bf((v0.y-mu)*rs*g0.y+b0.y);
  o0[2]=f2bf((v0.z-mu)*rs*g0.z+b0.z); o0[3]=f2bf((v0.w-mu)*rs*g0.w+b0.w);
  o1[0]=f2bf((v1.x-mu)*rs*g1.x+b1.x); o1[1]=f2bf((v1.y-mu)*rs*g1.y+b1.y);
  o1[2]=f2bf((v1.z-mu)*rs*g1.z+b1.z); o1[3]=f2bf((v1.w-mu)*rs*g1.w+b1.w);
  o2[0]=f2bf((v2.x-mu)*rs*g2.x+b2.x); o2[1]=f2bf((v2.y-mu)*rs*g2.y+b2.y);
  o2[2]=f2bf((v2.z-mu)*rs*g2.z+b2.z); o2[3]=f2bf((v2.w-mu)*rs*g2.w+b2.w);
  *reinterpret_cast<u16x4*>(op + lane*4)       = o0;
  *reinterpret_cast<u16x4*>(op + lane*4 + 256) = o1;
  *reinterpret_cast<u16x4*>(op + lane*4 + 512) = o2;
}

// ---------------- all 7 weight transposes in one launch ----------------
__device__ __forceinline__ void tr_tile(const float* __restrict__ in,
    u16* __restrict__ outp, int R, int Cc, int t)
{
  __shared__ float tile[32][33];
  const int tilesx = Cc >> 5;
  const int c0 = (t % tilesx)*32, r0 = (t / tilesx)*32;
  const int tx = threadIdx.x & 31, ty = threadIdx.x >> 5;
#pragma unroll
  for (int i=0;i<32;i+=8)
    tile[ty+i][tx] = in[(size_t)(r0+ty+i)*Cc + c0+tx];
  __syncthreads();
#pragma unroll
  for (int i=0;i<32;i+=8)
    outp[(size_t)(c0+ty+i)*R + r0+tx] = f2bf(tile[tx][ty+i]);
}

__global__ __launch_bounds__(256) void transpose_all(
    const float* Wk, const float* Wpx, const float* Wpy,
    const float* f1x, const float* f2x, const float* f1y, const float* f2y,
    u16* WkT, u16* WpxT, u16* WpyT, u16* f1xT, u16* f2xT, u16* f1yT, u16* f2yT)
{
  int t = blockIdx.x;
  if (t < 1728){
    const int m = t / 576; t -= m*576;
    const float* in = (m==0)?Wk:((m==1)?Wpx:Wpy);
    u16* o = (m==0)?WkT:((m==1)?WpxT:WpyT);
    tr_tile(in, o, C_, C_, t);
  } else {
    t -= 1728;
    const int m = t / 2304; t -= m*2304;
    if (m==0)      tr_tile(f1x, f1xT, C_, H_, t);
    else if (m==1) tr_tile(f2x, f2xT, H_, C_, t);
    else if (m==2) tr_tile(f1y, f1yT, C_, H_, t);
    else           tr_tile(f2y, f2yT, H_, C_, t);
  }
}

// ---------------- masked pooling partials of yn (+ mask partial) ----------------
__global__ __launch_bounds__(256) void pool_partial(const u16* __restrict__ q,
    const float* __restrict__ mask, float* __restrict__ pm, float* __restrict__ pa,
    float* __restrict__ mpart)
{
  const int c = blockIdx.x*256 + threadIdx.x;
  const int b = blockIdx.y, z = blockIdx.z;
  const int n0 = z*(N_/NSPLIT);
  const u16* qp = q + ((size_t)b*N_ + n0)*C_ + c;
  const float* mp = mask + (size_t)b*N_ + n0;
  float am=0.f, aa=0.f, ms=0.f;
  for (int n=0;n<N_/NSPLIT;n++){
    float v = bf2f(qp[(size_t)n*C_]);
    float m = mp[n];
    am += v*m; aa += v; ms += m;
  }
  const size_t o = ((size_t)z*B_ + b)*C_ + c;
  pm[o]=am; pa[o]=aa;
  if (blockIdx.x==0 && threadIdx.x==0) mpart[z*B_+b] = ms;
}

// ---------------- proto_fused: pool_final + (fg,bg)=pooled@Wq + norms ----------------
__global__ __launch_bounds__(256) void proto_fused(const float* __restrict__ pm,
    const float* __restrict__ pa, const float* __restrict__ mpart,
    const float* __restrict__ Wq,
    float* __restrict__ fg, float* __restrict__ bg,
    float* __restrict__ fgn, float* __restrict__ bgn)
{
  __shared__ float fin[C_], bin[C_];
  __shared__ float red[8];
  const int b = blockIdx.x, tid = threadIdx.x;
  float msum_b = 0.f;
#pragma unroll
  for (int z=0;z<NSPLIT;z++) msum_b += mpart[z*B_+b];
  for (int c=tid;c<C_;c+=256){
    float sm=0.f, sa=0.f;
#pragma unroll
    for (int z=0;z<NSPLIT;z++){ size_t o=((size_t)z*B_+b)*C_+c; sm+=pm[o]; sa+=pa[o]; }
    fin[c] = sm/(msum_b + 5e-4f);
    bin[c] = (sa - sm)/((float)N_ - msum_b + 5e-4f);
  }
  __syncthreads();
  const int j0 = tid, j1 = tid+256, j2 = tid+512;
  float f0=0,f1=0,f2=0,g0=0,g1=0,g2=0;
  for (int c=0;c<C_;c++){
    const float* w = Wq + (size_t)c*C_;
    float fc = fin[c], bc = bin[c];
    float w0=w[j0], w1=w[j1], w2=w[j2];
    f0 += fc*w0; f1 += fc*w1; f2 += fc*w2;
    g0 += bc*w0; g1 += bc*w1; g2 += bc*w2;
  }
  fg[b*C_+j0]=f0; fg[b*C_+j1]=f1; fg[b*C_+j2]=f2;
  bg[b*C_+j0]=g0; bg[b*C_+j1]=g1; bg[b*C_+j2]=g2;
  float sf = f0*f0+f1*f1+f2*f2, sb = g0*g0+g1*g1+g2*g2;
#pragma unroll
  for (int o=32;o>0;o>>=1){ sf+=__shfl_down(sf,o); sb+=__shfl_down(sb,o); }
  if ((tid&63)==0){ red[tid>>6]=sf; red[4+(tid>>6)]=sb; }
  __syncthreads();
  if (tid==0){
    fgn[b]=sqrtf(red[0]+red[1]+red[2]+red[3]);
    bgn[b]=sqrtf(red[4]+red[5]+red[6]+red[7]);
  }
}

// ---------------- cosine scores: wave-per-token ----------------
__global__ __launch_bounds__(256) void score_kernel(const u16* __restrict__ k,
    const float* __restrict__ fg, const float* __restrict__ bg,
    const float* __restrict__ fgn, const float* __restrict__ bgn,
    float* __restrict__ fg_s, float* __restrict__ bg_s)
{
  const int t = blockIdx.x*4 + (threadIdx.x >> 6);
  const int lane = threadIdx.x & 63;
  const int b = t >> 12;
  const u16* kp = k + (size_t)t*C_;
  u16x8 k8 = *reinterpret_cast<const u16x8*>(kp + lane*8);
  u16x4 k4 = *reinterpret_cast<const u16x4*>(kp + 512 + lane*4);
  const float* fgp = fg + b*C_;
  const float* bgp = bg + b*C_;
  float4 fa = *reinterpret_cast<const float4*>(fgp + lane*8);
  float4 fb = *reinterpret_cast<const float4*>(fgp + lane*8 + 4);
  float4 fc = *reinterpret_cast<const float4*>(fgp + 512 + lane*4);
  float4 ba = *reinterpret_cast<const float4*>(bgp + lane*8);
  float4 bb = *reinterpret_cast<const float4*>(bgp + lane*8 + 4);
  float4 bc = *reinterpret_cast<const float4*>(bgp + 512 + lane*4);
  float kv[12];
#pragma unroll
  for (int i=0;i<8;i++) kv[i] = bf2f(k8[i]);
#pragma unroll
  for (int i=0;i<4;i++) kv[8+i] = bf2f(k4[i]);
  float df = kv[0]*fa.x+kv[1]*fa.y+kv[2]*fa.z+kv[3]*fa.w
           + kv[4]*fb.x+kv[5]*fb.y+kv[6]*fb.z+kv[7]*fb.w
           + kv[8]*fc.x+kv[9]*fc.y+kv[10]*fc.z+kv[11]*fc.w;
  float db = kv[0]*ba.x+kv[1]*ba.y+kv[2]*ba.z+kv[3]*ba.w
           + kv[4]*bb.x+kv[5]*bb.y+kv[6]*bb.z+kv[7]*bb.w
           + kv[8]*bc.x+kv[9]*bc.y+kv[10]*bc.z+kv[11]*bc.w;
  float kk=0.f;
#pragma unroll
  for (int i=0;i<12;i++) kk += kv[i]*kv[i];
#pragma unroll
  for (int o=32;o>0;o>>=1){
    df+=__shfl_xor(df,o); db+=__shfl_xor(db,o); kk+=__shfl_xor(kk,o);
  }
  if (lane==0){
    const float kn = sqrtf(kk);
    fg_s[t] = df/(kn*fgn[b]+1e-7f);
    bg_s[t] = db/(kn*bgn[b]+1e-7f);
  }
}

__global__ __launch_bounds__(256) void minmax_kernel(const float* __restrict__ fg_s,
    const float* __restrict__ bg_s, float* __restrict__ mm)
{
  __shared__ float sm[16];
  const int b = blockIdx.x;
  float mnf=1e30f, mxf=-1e30f, mnb=1e30f, mxb=-1e30f;
  for (int i=threadIdx.x;i<N_;i+=256){
    float a = fg_s[(size_t)b*N_+i]; mnf=fminf(mnf,a); mxf=fmaxf(mxf,a);
    float c = bg_s[(size_t)b*N_+i]; mnb=fminf(mnb,c); mxb=fmaxf(mxb,c);
  }
#pragma unroll
  for (int o=32;o>0;o>>=1){
    mnf=fminf(mnf,__shfl_down(mnf,o)); mxf=fmaxf(mxf,__shfl_down(mxf,o));
    mnb=fminf(mnb,__shfl_down(mnb,o)); mxb=fmaxf(mxb,__shfl_down(mxb,o));
  }
  const int wid = threadIdx.x>>6;
  if ((threadIdx.x&63)==0){ sm[wid]=mnf; sm[4+wid]=mxf; sm[8+wid]=mnb; sm[12+wid]=mxb; }
  __syncthreads();
  if (threadIdx.x==0){
    mm[b*4+0]=fminf(fminf(sm[0],sm[1]),fminf(sm[2],sm[3]));
    mm[b*4+1]=fmaxf(fmaxf(sm[4],sm[5]),fmaxf(sm[6],sm[7]));
    mm[b*4+2]=fminf(fminf(sm[8],sm[9]),fminf(sm[10],sm[11]));
    mm[b*4+3]=fmaxf(fmaxf(sm[12],sm[13]),fmaxf(sm[14],sm[15]));
  }
}

// scores -> pseudo out + exp weights + denom, one block per b (1024 thr)
__global__ __launch_bounds__(1024) void scorefin_fused(const float* __restrict__ fg_s,
    const float* __restrict__ bg_s, const float* __restrict__ mm,
    float* __restrict__ pseudo, float* __restrict__ escr, float* __restrict__ denom)
{
  __shared__ float sm[16];
  const int b = blockIdx.x, tid = threadIdx.x;
  const float mnf=mm[b*4+0], mxf=mm[b*4+1], mnb=mm[b*4+2], mxb=mm[b*4+3];
  const float rf = 1.f/(mxf-mnf+1e-7f), rb = 1.f/(mxb-mnb+1e-7f);
  float ps = 0.f;
#pragma unroll
  for (int i=0;i<4;i++){
    const int t = tid + i*1024;
    const size_t o = (size_t)b*N_ + t;
    const float s = (fg_s[o]-mnf)*rf - (bg_s[o]-mnb)*rb;
    pseudo[o] = s;
    const float e = expf(s < 0.f ? s - 100.f : s);
    escr[o] = e;
    ps += e;
  }
#pragma unroll
  for (int o=32;o>0;o>>=1) ps += __shfl_down(ps,o);
  if ((tid&63)==0) sm[tid>>6]=ps;
  __syncthreads();
  if (tid==0){
    float s=0.f;
#pragma unroll
    for (int w=0;w<16;w++) s+=sm[w];
    denom[b]=s;
  }
}

// attn-pool partials of xn
__global__ __launch_bounds__(256) void vpool_partial(const u16* __restrict__ xn,
    const float* __restrict__ e, float* __restrict__ pv)
{
  const int c = blockIdx.x*256 + threadIdx.x;
  const int b = blockIdx.y, z = blockIdx.z;
  const int n0 = z*(N_/NSPLIT);
  const u16* vp = xn + ((size_t)b*N_ + n0)*C_ + c;
  const float* ep = e + (size_t)b*N_ + n0;
  float acc=0.f;
  for (int n=0;n<N_/NSPLIT;n++) acc += bf2f(vp[(size_t)n*C_])*ep[n];
  pv[((size_t)z*B_+b)*C_+c] = acc;
}

// pro_fused: vpool_final + qp=vin@Wv + sim + pro + rowx/rowy = pro@Wp*B
__global__ __launch_bounds__(256) void pro_fused(const float* __restrict__ pv,
    const float* __restrict__ denom,
    const float* __restrict__ Wv, const float* __restrict__ Wpx,
    const float* __restrict__ Wpy,
    const float* __restrict__ fg, const float* __restrict__ fgn,
    float* __restrict__ rowx, float* __restrict__ rowy)
{
  __shared__ float vin[C_];
  __shared__ float red[8];
  __shared__ float simsh;
  const int b = blockIdx.x, tid = threadIdx.x;
  const float den = 1.f/denom[b];
  for (int c=tid;c<C_;c+=256){
    float s=0.f;
#pragma unroll
    for (int z=0;z<NSPLIT;z++) s += pv[((size_t)z*B_+b)*C_+c];
    vin[c] = s*den;
  }
  __syncthreads();
  const int j0 = tid, j1 = tid+256, j2 = tid+512;
  float q0=0,q1=0,q2=0;
  for (int c=0;c<C_;c++){
    const float* w = Wv + (size_t)c*C_;
    float vv = vin[c];
    q0 += vv*w[j0]; q1 += vv*w[j1]; q2 += vv*w[j2];
  }
  const float fg0 = fg[b*C_+j0], fg1 = fg[b*C_+j1], fg2 = fg[b*C_+j2];
  float d = q0*fg0 + q1*fg1 + q2*fg2;
  float qq = q0*q0 + q1*q1 + q2*q2;
#pragma unroll
  for (int o=32;o>0;o>>=1){ d+=__shfl_down(d,o); qq+=__shfl_down(qq,o); }
  if ((tid&63)==0){ red[tid>>6]=d; red[4+(tid>>6)]=qq; }
  __syncthreads();
  if (tid==0){
    float dd=red[0]+red[1]+red[2]+red[3], qs=red[4]+red[5]+red[6]+red[7];
    simsh = (dd/(sqrtf(qs)*fgn[b]+1e-7f)+1.f)*0.5f;
  }
  __syncthreads();
  const float sim = simsh;
  vin[j0] = sim*fg0 + (1.f-sim)*q0;
  vin[j1] = sim*fg1 + (1.f-sim)*q1;
  vin[j2] = sim*fg2 + (1.f-sim)*q2;
  __syncthreads();
  float rx0=0,rx1=0,rx2=0, ry0=0,ry1=0,ry2=0;
  for (int c=0;c<C_;c++){
    const float* wx = Wpx + (size_t)(C_+c)*C_;
    const float* wy = Wpy + (size_t)(C_+c)*C_;
    float pc = vin[c];
    rx0 += pc*wx[j0]; rx1 += pc*wx[j1]; rx2 += pc*wx[j2];
    ry0 += pc*wy[j0]; ry1 += pc*wy[j1]; ry2 += pc*wy[j2];
  }
  rowx[b*C_+j0]=rx0; rowx[b*C_+j1]=rx1; rowx[b*C_+j2]=rx2;
  rowy[b*C_+j0]=ry0; rowy[b*C_+j1]=ry1; rowy[b*C_+j2]=ry2;
}

// ---------------- launcher ----------------
extern "C" void kernel_launch(void* const* d_in, const int* in_sizes, int n_in,
                              void* d_out, int out_size, void* d_ws, size_t ws_size,
                              hipStream_t stream)
{
  const float* x     = (const float*)d_in[0];
  const float* y     = (const float*)d_in[1];
  const float* mask  = (const float*)d_in[2];
  const float* ln1_g = (const float*)d_in[5];
  const float* ln1_b = (const float*)d_in[6];
  const float* Wq    = (const float*)d_in[7];
  const float* Wk    = (const float*)d_in[8];
  const float* Wv    = (const float*)d_in[9];
  const float* Wpx   = (const float*)d_in[10];
  const float* Wpy   = (const float*)d_in[11];
  const float* ln2_g = (const float*)d_in[12];
  const float* ln2_b = (const float*)d_in[13];
  const float* fx1_w = (const float*)d_in[14];
  const float* fx1_b = (const float*)d_in[15];
  const float* fx2_w = (const float*)d_in[16];
  const float* fx2_b = (const float*)d_in[17];
  const float* fy1_w = (const float*)d_in[18];
  const float* fy1_b = (const float*)d_in[19];
  const float* fy2_w = (const float*)d_in[20];
  const float* fy2_b = (const float*)d_in[21];

  float* out    = (float*)d_out;
  float* out_xo = out;
  float* out_yo = out + (size_t)M_*C_;
  float* out_ps = out + 2*(size_t)M_*C_;

  char* ws = (char*)d_ws;
  const size_t ACT = (size_t)M_*C_;
  u16* R0  = (u16*)ws;
  u16* xnb = R0;                           // slot0: xn
  u16* ynb = R0 + ACT;                     // slot1: yn
  u16* kb  = R0 + 2*ACT;                   // slot2: k
  u16* xb  = R0 + 3*ACT;                   // slot3: x bf16 (dead after proj)
  u16* yb  = (u16*)(ws + 4*ACT*2);         // slot4: y bf16 (dead after proj)
  u16* qb  = yb;                           // slot4 reused: ln2 out
  u16* hid = R0;                           // MLP hidden aliases slots 0-3
  u16* wp  = (u16*)(ws + 5*ACT*2);
  u16* WkT  = wp;
  u16* WpxT = wp + 1*589824;
  u16* WpyT = wp + 2*589824;
  u16* fx1T = wp + 3*589824;
  u16* fx2T = fx1T + 2359296;
  u16* fy1T = fx2T + 2359296;
  u16* fy2T = fy1T + 2359296;
  float* st   = (float*)(ws + 5*ACT*2 + (size_t)(3*589824 + 4*2359296)*2);
  float* fgn  = st + 8;
  float* bgn  = st + 16;
  float* denom= st + 24;
  float* mm   = st + 32;
  float* fg   = st + 64;
  float* bg   = st + 6208;
  float* rowx = st + 24640;
  float* rowy = st + 30784;
  float* fg_s = st + 37056;
  float* bg_s = st + 69824;
  float* escr = st + 102592;
  float* pm   = st + 135360;
  float* pa   = st + 233664;
  float* pv   = st + 331968;
  float* mpart= st + 430272;

  dim3 tb(256);
  dim3 tg(512);

  // --- weights -> bf16 [N,K] + LN1(x,y) (also emits raw bf16 x,y) ---
  transpose_all<<<dim3(10944),tb,0,stream>>>(Wk,Wpx,Wpy,fx1_w,fx2_w,fy1_w,fy2_w,
                                             WkT,WpxT,WpyT,fx1T,fx2T,fy1T,fy2T);
  ln_fwd2<<<dim3(M_/4,2),tb,0,stream>>>(x, y, ln1_g, ln1_b, xnb, ynb, xb, yb);

  // --- k GEMM (q,v eliminated by pooling linearity) ---
  gemm_bf16<0,8,0><<<dim3(128*6),tg,0,stream>>>(xnb, WkT, C_, C_, 6, kb,
      nullptr,nullptr,nullptr, nullptr,nullptr,nullptr,nullptr,nullptr);

  // --- prototypes fg,bg (f32 path) ---
  pool_partial<<<dim3(3,B_,NSPLIT),tb,0,stream>>>(ynb, mask, pm, pa, mpart);
  proto_fused<<<B_,tb,0,stream>>>(pm, pa, mpart, Wq, fg, bg, fgn, bgn);

  // --- cosine scores + softmax weights ---
  score_kernel<<<M_/4,tb,0,stream>>>(kb, fg, bg, fgn, bgn, fg_s, bg_s);
  minmax_kernel<<<B_,tb,0,stream>>>(fg_s, bg_s, mm);
  scorefin_fused<<<B_,dim3(1024),0,stream>>>(fg_s, bg_s, mm, out_ps, escr, denom);

  // --- query_pro path + pro + row-vectors ---
  vpool_partial<<<dim3(3,B_,NSPLIT),tb,0,stream>>>(xnb, escr, pv);
  pro_fused<<<B_,tb,0,stream>>>(pv, denom, Wv, Wpx, Wpy, fg, fgn, rowx, rowy);

  // --- projection GEMMs, BATCHED x+y (kills the 1.5-round tail) ---
  gemm_bf16<1,8,1><<<dim3(128*6,2),tg,0,stream>>>(xb, WpxT, C_, C_, 6, out_xo,
      x, rowx, nullptr, yb, WpyT, out_yo, y, rowy);

  // --- x MLP ---
  ln_fwd<<<M_/4,tb,0,stream>>>(out_xo, ln2_g, ln2_b, qb);
  gemm_bf16<2,8,0><<<dim3(128*24),tg,0,stream>>>(qb, fx1T, C_, H_, 24, hid,
      nullptr,nullptr, fx1_b, nullptr,nullptr,nullptr,nullptr,nullptr);
  gemm_bf16<3,2,0><<<dim3(128*6),tg,0,stream>>>(hid, fx2T, H_, C_, 6, out_xo,
      nullptr,nullptr, fx2_b, nullptr,nullptr,nullptr,nullptr,nullptr);

  // --- y MLP ---
  ln_fwd<<<M_/4,tb,0,stream>>>(out_yo, ln2_g, ln2_b, qb);
  gemm_bf16<2,8,0><<<dim3(128*24),tg,0,stream>>>(qb, fy1T, C_, H_, 24, hid,
      nullptr,nullptr, fy1_b, nullptr,nullptr,nullptr,nullptr,nullptr);
  gemm_bf16<3,2,0><<<dim3(128*6),tg,0,stream>>>(hid, fy2T, H_, C_, 6, out_yo,
      nullptr,nullptr, fy2_b, nullptr,nullptr,nullptr,nullptr,nullptr);
}

// Round 12
// 1522.714 us; speedup vs baseline: 1.1518x; 1.0301x over previous
//
#include <hip/hip_runtime.h>
#include <math.h>

#define B_ 8
#define N_ 4096
#define C_ 768
#define H_ 3072
#define M_ (B_*N_)
#define NSPLIT 16

typedef unsigned short u16;
typedef unsigned int u32;
typedef __attribute__((ext_vector_type(8))) __bf16 bf16x8;
typedef __attribute__((ext_vector_type(4))) float f32x4;
typedef __attribute__((ext_vector_type(4))) unsigned short u16x4;
typedef __attribute__((ext_vector_type(8))) unsigned short u16x8;

__device__ __forceinline__ u16 f2bf(float f){
  u32 u = __float_as_uint(f);
  u32 r = (u + 0x7FFFu + ((u >> 16) & 1u)) >> 16;
  return (u16)r;
}
__device__ __forceinline__ float bf2f(u16 h){
  return __uint_as_float(((u32)h) << 16);
}
__device__ __forceinline__ void gload_lds16(const void* g, void* l){
  __builtin_amdgcn_global_load_lds((const __attribute__((address_space(1))) void*)g,
                                   (__attribute__((address_space(3))) void*)l, 16, 0, 0);
}

// ---------------- GEMM: C[M,N] = A[M,K](bf16) * BT[N,K](bf16)^T ----------------
// R9 kernel (best measured: 663 TF, the 2-phase structural plateau).
// 256x128 tile, 512 thr = 8 waves (4M x 2N), TRIPLE-buffered LDS, 2-deep
// prefetch, counted s_waitcnt vmcnt(3) (T4), K-loop unrolled x3 (literal
// buffer indices; VALU 70->11%), LDS XOR swizzle both-sides (conflicts=0).
// Stores CACHED (R7: nt stores -> partial-line writeback, +50% WRITE_SIZE).
// nt loads only on read-once f32 (resid / RMW prev).
// Session-verified nulls: GM=2 for K=3072 (R8), batched-pair launch (R11),
// 8-phase ports x3 (R3/R10: 520-540 TF, catalog's open m232 quadrant).
// EPI: 0=bf16 out; 1=f32 resid+acc+rowv; 2=bf16 gelu(acc+bias); 3=f32 +=acc+bias
template<int EPI, int GM>
__global__ __launch_bounds__(512, 4) void gemm_bf16(
    const u16* __restrict__ A, const u16* __restrict__ BT,
    int K, int N, int NBN,
    void* __restrict__ outp,
    const float* __restrict__ resid,
    const float* __restrict__ rowv,
    const float* __restrict__ bias)
{
  __shared__ u16 lds[3][12288];
  const int tid = threadIdx.x;
  const int wid = tid >> 6, lane = tid & 63;

  // block swizzle: XCD chunk (nwg%8==0) + GM row-panel grouping
  const int nwg = gridDim.x;
  int wg = blockIdx.x;
  wg = (wg & 7) * (nwg >> 3) + (wg >> 3);
  const int GMN = GM * NBN;
  const int g = wg / GMN, r = wg % GMN;
  const int bm = (g*GM + (r % GM)) * 256;
  const int bn = (r / GM) * 128;

  const int wr = wid >> 1, wc = wid & 1;
  const int l15 = lane & 15;

  f32x4 acc[4][4];
#pragma unroll
  for (int i=0;i<4;i++)
#pragma unroll
    for (int j=0;j<4;j++) acc[i][j] = (f32x4){0.f,0.f,0.f,0.f};

  // staging: slot tid -> row tid>>2, phys chunk tid&3; logical chunk pre-swizzled
  const int srow = tid >> 2;
  const int lchq = (tid & 3) ^ ((tid >> 3) & 3);     // (tid&3) ^ ((srow>>1)&3)
  const u16* agp0 = A  + (size_t)(bm + srow)*K       + lchq*8;
  const u16* agp1 = A  + (size_t)(bm + 128 + srow)*K + lchq*8;
  const u16* bgp0 = BT + (size_t)(bn + srow)*K       + lchq*8;

  auto STAGE = [&](int bi){
    char* base = (char*)lds[bi] + wid*1024;   // wave-uniform base; HW adds lane*16
    gload_lds16(agp0, base);
    gload_lds16(agp1, base + 8192);
    gload_lds16(bgp0, base + 16384);
    agp0 += 32; agp1 += 32; bgp0 += 32;
  };

  // swizzled read offsets (u16 units); swz invariant across i (row step 16)
  const int arow = wr*64 + l15;
  const int brow = wc*64 + l15;
  const int aswz = (arow >> 1) & 3;
  const int bswz = (brow >> 1) & 3;
  const int aoff = arow*32 + (((lane>>4) ^ aswz) << 3);
  const int boff = 8192 + brow*32 + (((lane>>4) ^ bswz) << 3);

  const int nk = K >> 5;    // K=768 -> 24, K=3072 -> 96; both divisible by 3
  STAGE(0);
  STAGE(1);
  int kk2 = 0;

#define KSTEP(BI) do {                                                        \
    if (kk2 == nk-1){ asm volatile("s_waitcnt vmcnt(0)" ::: "memory"); }      \
    else            { asm volatile("s_waitcnt vmcnt(3)" ::: "memory"); }      \
    __builtin_amdgcn_s_barrier();                                             \
    __builtin_amdgcn_sched_barrier(0);                                        \
    if (kk2+2 < nk) STAGE((BI)==0 ? 2 : (BI)-1);  /* buf (kk+2)%3 */          \
    bf16x8 av[4], bv[4];                                                      \
    const u16* pa = &lds[BI][aoff];                                           \
    const u16* pb = &lds[BI][boff];                                           \
    _Pragma("unroll")                                                         \
    for (int i=0;i<4;i++){                                                    \
      av[i] = *reinterpret_cast<const bf16x8*>(pa + i*512);                   \
      bv[i] = *reinterpret_cast<const bf16x8*>(pb + i*512);                   \
    }                                                                         \
    _Pragma("unroll")                                                         \
    for (int i=0;i<4;i++)                                                     \
      _Pragma("unroll")                                                       \
      for (int j=0;j<4;j++)                                                   \
        acc[i][j] = __builtin_amdgcn_mfma_f32_16x16x32_bf16(av[i], bv[j],     \
                                                            acc[i][j],0,0,0); \
    kk2++;                                                                    \
  } while(0)

  for (int it = 0; it < nk/3; it++){
    KSTEP(0);
    KSTEP(1);
    KSTEP(2);
  }
#undef KSTEP

  // C/D layout (verified m89): col = lane&15, row = (lane>>4)*4 + r
  const int col0 = bn + wc*64 + l15;
  const int row0 = bm + wr*64 + ((lane >> 4) << 2);
#pragma unroll
  for (int i=0;i<4;i++){
#pragma unroll
    for (int j=0;j<4;j++){
#pragma unroll
      for (int r2=0;r2<4;r2++){
        const int row = row0 + i*16 + r2;
        const int cj  = col0 + j*16;
        const size_t o = (size_t)row*N + cj;
        const float va = acc[i][j][r2];
        if constexpr (EPI == 0){
          ((u16*)outp)[o] = f2bf(va);
        } else if constexpr (EPI == 1){
          const float rs = __builtin_nontemporal_load(resid + o);
          ((float*)outp)[o] = rs + va + rowv[(row >> 12)*N + cj];
        } else if constexpr (EPI == 2){
          const float z = va + bias[cj];
          ((u16*)outp)[o] = f2bf(0.5f*z*(1.0f + erff(z*0.70710678f)));
        } else {
          float* po = (float*)outp + o;
          const float prev = __builtin_nontemporal_load(po);
          *po = prev + va + bias[cj];
        }
      }
    }
  }
}

// ---------------- LayerNorm over last dim (768): wave-per-row, float4 ----------------
__device__ __forceinline__ void ln_row(const float* __restrict__ p,
    const float* __restrict__ gam, const float* __restrict__ bet,
    u16* __restrict__ op, int lane)
{
  float4 v0 = *reinterpret_cast<const float4*>(p + lane*4);
  float4 v1 = *reinterpret_cast<const float4*>(p + lane*4 + 256);
  float4 v2 = *reinterpret_cast<const float4*>(p + lane*4 + 512);
  float s  = v0.x+v0.y+v0.z+v0.w + v1.x+v1.y+v1.z+v1.w + v2.x+v2.y+v2.z+v2.w;
  float sq = v0.x*v0.x+v0.y*v0.y+v0.z*v0.z+v0.w*v0.w
           + v1.x*v1.x+v1.y*v1.y+v1.z*v1.z+v1.w*v1.w
           + v2.x*v2.x+v2.y*v2.y+v2.z*v2.z+v2.w*v2.w;
#pragma unroll
  for (int o=32;o>0;o>>=1){ s += __shfl_xor(s,o); sq += __shfl_xor(sq,o); }
  const float mu = s * (1.f/C_);
  const float rs = rsqrtf(sq*(1.f/C_) - mu*mu + 1e-5f);
  float4 g0 = *reinterpret_cast<const float4*>(gam + lane*4);
  float4 g1 = *reinterpret_cast<const float4*>(gam + lane*4 + 256);
  float4 g2 = *reinterpret_cast<const float4*>(gam + lane*4 + 512);
  float4 b0 = *reinterpret_cast<const float4*>(bet + lane*4);
  float4 b1 = *reinterpret_cast<const float4*>(bet + lane*4 + 256);
  float4 b2 = *reinterpret_cast<const float4*>(bet + lane*4 + 512);
  u16x4 o0, o1, o2;
  o0[0]=f2bf((v0.x-mu)*rs*g0.x+b0.x); o0[1]=f2bf((v0.y-mu)*rs*g0.y+b0.y);
  o0[2]=f2bf((v0.z-mu)*rs*g0.z+b0.z); o0[3]=f2bf((v0.w-mu)*rs*g0.w+b0.w);
  o1[0]=f2bf((v1.x-mu)*rs*g1.x+b1.x); o1[1]=f2bf((v1.y-mu)*rs*g1.y+b1.y);
  o1[2]=f2bf((v1.z-mu)*rs*g1.z+b1.z); o1[3]=f2bf((v1.w-mu)*rs*g1.w+b1.w);
  o2[0]=f2bf((v2.x-mu)*rs*g2.x+b2.x); o2[1]=f2bf((v2.y-mu)*rs*g2.y+b2.y);
  o2[2]=f2bf((v2.z-mu)*rs*g2.z+b2.z); o2[3]=f2bf((v2.w-mu)*rs*g2.w+b2.w);
  *reinterpret_cast<u16x4*>(op + lane*4)       = o0;
  *reinterpret_cast<u16x4*>(op + lane*4 + 256) = o1;
  *reinterpret_cast<u16x4*>(op + lane*4 + 512) = o2;
}

__global__ __launch_bounds__(256) void ln_fwd(const float* __restrict__ in,
    const float* __restrict__ gam, const float* __restrict__ bet,
    u16* __restrict__ out)
{
  const int row  = blockIdx.x*4 + (threadIdx.x >> 6);
  const int lane = threadIdx.x & 63;
  ln_row(in + (size_t)row*C_, gam, bet, out + (size_t)row*C_, lane);
}

// LN1 for x and y; ALSO emits raw bf16 cast of the input (saves the cvt pass)
__global__ __launch_bounds__(256) void ln_fwd2(const float* __restrict__ inx,
    const float* __restrict__ iny, const float* __restrict__ gam,
    const float* __restrict__ bet, u16* __restrict__ outx, u16* __restrict__ outy,
    u16* __restrict__ outxb, u16* __restrict__ outyb)
{
  const int row  = blockIdx.x*4 + (threadIdx.x >> 6);
  const int lane = threadIdx.x & 63;
  const float* in = blockIdx.y ? iny : inx;
  u16* out  = blockIdx.y ? outy  : outx;
  u16* outb = blockIdx.y ? outyb : outxb;
  const float* p = in + (size_t)row*C_;
  u16* op  = out  + (size_t)row*C_;
  u16* opb = outb + (size_t)row*C_;

  float4 v0 = *reinterpret_cast<const float4*>(p + lane*4);
  float4 v1 = *reinterpret_cast<const float4*>(p + lane*4 + 256);
  float4 v2 = *reinterpret_cast<const float4*>(p + lane*4 + 512);
  u16x4 rb;
  rb[0]=f2bf(v0.x); rb[1]=f2bf(v0.y); rb[2]=f2bf(v0.z); rb[3]=f2bf(v0.w);
  *reinterpret_cast<u16x4*>(opb + lane*4) = rb;
  rb[0]=f2bf(v1.x); rb[1]=f2bf(v1.y); rb[2]=f2bf(v1.z); rb[3]=f2bf(v1.w);
  *reinterpret_cast<u16x4*>(opb + lane*4 + 256) = rb;
  rb[0]=f2bf(v2.x); rb[1]=f2bf(v2.y); rb[2]=f2bf(v2.z); rb[3]=f2bf(v2.w);
  *reinterpret_cast<u16x4*>(opb + lane*4 + 512) = rb;

  float s  = v0.x+v0.y+v0.z+v0.w + v1.x+v1.y+v1.z+v1.w + v2.x+v2.y+v2.z+v2.w;
  float sq = v0.x*v0.x+v0.y*v0.y+v0.z*v0.z+v0.w*v0.w
           + v1.x*v1.x+v1.y*v1.y+v1.z*v1.z+v1.w*v1.w
           + v2.x*v2.x+v2.y*v2.y+v2.z*v2.z+v2.w*v2.w;
#pragma unroll
  for (int o=32;o>0;o>>=1){ s += __shfl_xor(s,o); sq += __shfl_xor(sq,o); }
  const float mu = s * (1.f/C_);
  const float rs = rsqrtf(sq*(1.f/C_) - mu*mu + 1e-5f);
  float4 g0 = *reinterpret_cast<const float4*>(gam + lane*4);
  float4 g1 = *reinterpret_cast<const float4*>(gam + lane*4 + 256);
  float4 g2 = *reinterpret_cast<const float4*>(gam + lane*4 + 512);
  float4 b0 = *reinterpret_cast<const float4*>(bet + lane*4);
  float4 b1 = *reinterpret_cast<const float4*>(bet + lane*4 + 256);
  float4 b2 = *reinterpret_cast<const float4*>(bet + lane*4 + 512);
  u16x4 o0, o1, o2;
  o0[0]=f2bf((v0.x-mu)*rs*g0.x+b0.x); o0[1]=f2bf((v0.y-mu)*rs*g0.y+b0.y);
  o0[2]=f2bf((v0.z-mu)*rs*g0.z+b0.z); o0[3]=f2bf((v0.w-mu)*rs*g0.w+b0.w);
  o1[0]=f2bf((v1.x-mu)*rs*g1.x+b1.x); o1[1]=f2bf((v1.y-mu)*rs*g1.y+b1.y);
  o1[2]=f2bf((v1.z-mu)*rs*g1.z+b1.z); o1[3]=f2bf((v1.w-mu)*rs*g1.w+b1.w);
  o2[0]=f2bf((v2.x-mu)*rs*g2.x+b2.x); o2[1]=f2bf((v2.y-mu)*rs*g2.y+b2.y);
  o2[2]=f2bf((v2.z-mu)*rs*g2.z+b2.z); o2[3]=f2bf((v2.w-mu)*rs*g2.w+b2.w);
  *reinterpret_cast<u16x4*>(op + lane*4)       = o0;
  *reinterpret_cast<u16x4*>(op + lane*4 + 256) = o1;
  *reinterpret_cast<u16x4*>(op + lane*4 + 512) = o2;
}

// ---------------- all 7 weight transposes in one launch ----------------
__device__ __forceinline__ void tr_tile(const float* __restrict__ in,
    u16* __restrict__ outp, int R, int Cc, int t)
{
  __shared__ float tile[32][33];
  const int tilesx = Cc >> 5;
  const int c0 = (t % tilesx)*32, r0 = (t / tilesx)*32;
  const int tx = threadIdx.x & 31, ty = threadIdx.x >> 5;
#pragma unroll
  for (int i=0;i<32;i+=8)
    tile[ty+i][tx] = in[(size_t)(r0+ty+i)*Cc + c0+tx];
  __syncthreads();
#pragma unroll
  for (int i=0;i<32;i+=8)
    outp[(size_t)(c0+ty+i)*R + r0+tx] = f2bf(tile[tx][ty+i]);
}

__global__ __launch_bounds__(256) void transpose_all(
    const float* Wk, const float* Wpx, const float* Wpy,
    const float* f1x, const float* f2x, const float* f1y, const float* f2y,
    u16* WkT, u16* WpxT, u16* WpyT, u16* f1xT, u16* f2xT, u16* f1yT, u16* f2yT)
{
  int t = blockIdx.x;
  if (t < 1728){
    const int m = t / 576; t -= m*576;
    const float* in = (m==0)?Wk:((m==1)?Wpx:Wpy);
    u16* o = (m==0)?WkT:((m==1)?WpxT:WpyT);
    tr_tile(in, o, C_, C_, t);
  } else {
    t -= 1728;
    const int m = t / 2304; t -= m*2304;
    if (m==0)      tr_tile(f1x, f1xT, C_, H_, t);
    else if (m==1) tr_tile(f2x, f2xT, H_, C_, t);
    else if (m==2) tr_tile(f1y, f1yT, C_, H_, t);
    else           tr_tile(f2y, f2yT, H_, C_, t);
  }
}

// ---------------- masked pooling partials of yn (+ mask partial) ----------------
__global__ __launch_bounds__(256) void pool_partial(const u16* __restrict__ q,
    const float* __restrict__ mask, float* __restrict__ pm, float* __restrict__ pa,
    float* __restrict__ mpart)
{
  const int c = blockIdx.x*256 + threadIdx.x;
  const int b = blockIdx.y, z = blockIdx.z;
  const int n0 = z*(N_/NSPLIT);
  const u16* qp = q + ((size_t)b*N_ + n0)*C_ + c;
  const float* mp = mask + (size_t)b*N_ + n0;
  float am=0.f, aa=0.f, ms=0.f;
  for (int n=0;n<N_/NSPLIT;n++){
    float v = bf2f(qp[(size_t)n*C_]);
    float m = mp[n];
    am += v*m; aa += v; ms += m;
  }
  const size_t o = ((size_t)z*B_ + b)*C_ + c;
  pm[o]=am; pa[o]=aa;
  if (blockIdx.x==0 && threadIdx.x==0) mpart[z*B_+b] = ms;
}

// ---------------- proto_fused: pool_final + (fg,bg)=pooled@Wq + norms ----------------
__global__ __launch_bounds__(256) void proto_fused(const float* __restrict__ pm,
    const float* __restrict__ pa, const float* __restrict__ mpart,
    const float* __restrict__ Wq,
    float* __restrict__ fg, float* __restrict__ bg,
    float* __restrict__ fgn, float* __restrict__ bgn)
{
  __shared__ float fin[C_], bin[C_];
  __shared__ float red[8];
  const int b = blockIdx.x, tid = threadIdx.x;
  float msum_b = 0.f;
#pragma unroll
  for (int z=0;z<NSPLIT;z++) msum_b += mpart[z*B_+b];
  for (int c=tid;c<C_;c+=256){
    float sm=0.f, sa=0.f;
#pragma unroll
    for (int z=0;z<NSPLIT;z++){ size_t o=((size_t)z*B_+b)*C_+c; sm+=pm[o]; sa+=pa[o]; }
    fin[c] = sm/(msum_b + 5e-4f);
    bin[c] = (sa - sm)/((float)N_ - msum_b + 5e-4f);
  }
  __syncthreads();
  const int j0 = tid, j1 = tid+256, j2 = tid+512;
  float f0=0,f1=0,f2=0,g0=0,g1=0,g2=0;
  for (int c=0;c<C_;c++){
    const float* w = Wq + (size_t)c*C_;
    float fc = fin[c], bc = bin[c];
    float w0=w[j0], w1=w[j1], w2=w[j2];
    f0 += fc*w0; f1 += fc*w1; f2 += fc*w2;
    g0 += bc*w0; g1 += bc*w1; g2 += bc*w2;
  }
  fg[b*C_+j0]=f0; fg[b*C_+j1]=f1; fg[b*C_+j2]=f2;
  bg[b*C_+j0]=g0; bg[b*C_+j1]=g1; bg[b*C_+j2]=g2;
  float sf = f0*f0+f1*f1+f2*f2, sb = g0*g0+g1*g1+g2*g2;
#pragma unroll
  for (int o=32;o>0;o>>=1){ sf+=__shfl_down(sf,o); sb+=__shfl_down(sb,o); }
  if ((tid&63)==0){ red[tid>>6]=sf; red[4+(tid>>6)]=sb; }
  __syncthreads();
  if (tid==0){
    fgn[b]=sqrtf(red[0]+red[1]+red[2]+red[3]);
    bgn[b]=sqrtf(red[4]+red[5]+red[6]+red[7]);
  }
}

// ---------------- cosine scores: wave-per-token ----------------
__global__ __launch_bounds__(256) void score_kernel(const u16* __restrict__ k,
    const float* __restrict__ fg, const float* __restrict__ bg,
    const float* __restrict__ fgn, const float* __restrict__ bgn,
    float* __restrict__ fg_s, float* __restrict__ bg_s)
{
  const int t = blockIdx.x*4 + (threadIdx.x >> 6);
  const int lane = threadIdx.x & 63;
  const int b = t >> 12;
  const u16* kp = k + (size_t)t*C_;
  u16x8 k8 = *reinterpret_cast<const u16x8*>(kp + lane*8);
  u16x4 k4 = *reinterpret_cast<const u16x4*>(kp + 512 + lane*4);
  const float* fgp = fg + b*C_;
  const float* bgp = bg + b*C_;
  float4 fa = *reinterpret_cast<const float4*>(fgp + lane*8);
  float4 fb = *reinterpret_cast<const float4*>(fgp + lane*8 + 4);
  float4 fc = *reinterpret_cast<const float4*>(fgp + 512 + lane*4);
  float4 ba = *reinterpret_cast<const float4*>(bgp + lane*8);
  float4 bb = *reinterpret_cast<const float4*>(bgp + lane*8 + 4);
  float4 bc = *reinterpret_cast<const float4*>(bgp + 512 + lane*4);
  float kv[12];
#pragma unroll
  for (int i=0;i<8;i++) kv[i] = bf2f(k8[i]);
#pragma unroll
  for (int i=0;i<4;i++) kv[8+i] = bf2f(k4[i]);
  float df = kv[0]*fa.x+kv[1]*fa.y+kv[2]*fa.z+kv[3]*fa.w
           + kv[4]*fb.x+kv[5]*fb.y+kv[6]*fb.z+kv[7]*fb.w
           + kv[8]*fc.x+kv[9]*fc.y+kv[10]*fc.z+kv[11]*fc.w;
  float db = kv[0]*ba.x+kv[1]*ba.y+kv[2]*ba.z+kv[3]*ba.w
           + kv[4]*bb.x+kv[5]*bb.y+kv[6]*bb.z+kv[7]*bb.w
           + kv[8]*bc.x+kv[9]*bc.y+kv[10]*bc.z+kv[11]*bc.w;
  float kk=0.f;
#pragma unroll
  for (int i=0;i<12;i++) kk += kv[i]*kv[i];
#pragma unroll
  for (int o=32;o>0;o>>=1){
    df+=__shfl_xor(df,o); db+=__shfl_xor(db,o); kk+=__shfl_xor(kk,o);
  }
  if (lane==0){
    const float kn = sqrtf(kk);
    fg_s[t] = df/(kn*fgn[b]+1e-7f);
    bg_s[t] = db/(kn*bgn[b]+1e-7f);
  }
}

__global__ __launch_bounds__(256) void minmax_kernel(const float* __restrict__ fg_s,
    const float* __restrict__ bg_s, float* __restrict__ mm)
{
  __shared__ float sm[16];
  const int b = blockIdx.x;
  float mnf=1e30f, mxf=-1e30f, mnb=1e30f, mxb=-1e30f;
  for (int i=threadIdx.x;i<N_;i+=256){
    float a = fg_s[(size_t)b*N_+i]; mnf=fminf(mnf,a); mxf=fmaxf(mxf,a);
    float c = bg_s[(size_t)b*N_+i]; mnb=fminf(mnb,c); mxb=fmaxf(mxb,c);
  }
#pragma unroll
  for (int o=32;o>0;o>>=1){
    mnf=fminf(mnf,__shfl_down(mnf,o)); mxf=fmaxf(mxf,__shfl_down(mxf,o));
    mnb=fminf(mnb,__shfl_down(mnb,o)); mxb=fmaxf(mxb,__shfl_down(mxb,o));
  }
  const int wid = threadIdx.x>>6;
  if ((threadIdx.x&63)==0){ sm[wid]=mnf; sm[4+wid]=mxf; sm[8+wid]=mnb; sm[12+wid]=mxb; }
  __syncthreads();
  if (threadIdx.x==0){
    mm[b*4+0]=fminf(fminf(sm[0],sm[1]),fminf(sm[2],sm[3]));
    mm[b*4+1]=fmaxf(fmaxf(sm[4],sm[5]),fmaxf(sm[6],sm[7]));
    mm[b*4+2]=fminf(fminf(sm[8],sm[9]),fminf(sm[10],sm[11]));
    mm[b*4+3]=fmaxf(fmaxf(sm[12],sm[13]),fmaxf(sm[14],sm[15]));
  }
}

// scores -> pseudo out + exp weights + denom, one block per b (1024 thr)
__global__ __launch_bounds__(1024) void scorefin_fused(const float* __restrict__ fg_s,
    const float* __restrict__ bg_s, const float* __restrict__ mm,
    float* __restrict__ pseudo, float* __restrict__ escr, float* __restrict__ denom)
{
  __shared__ float sm[16];
  const int b = blockIdx.x, tid = threadIdx.x;
  const float mnf=mm[b*4+0], mxf=mm[b*4+1], mnb=mm[b*4+2], mxb=mm[b*4+3];
  const float rf = 1.f/(mxf-mnf+1e-7f), rb = 1.f/(mxb-mnb+1e-7f);
  float ps = 0.f;
#pragma unroll
  for (int i=0;i<4;i++){
    const int t = tid + i*1024;
    const size_t o = (size_t)b*N_ + t;
    const float s = (fg_s[o]-mnf)*rf - (bg_s[o]-mnb)*rb;
    pseudo[o] = s;
    const float e = expf(s < 0.f ? s - 100.f : s);
    escr[o] = e;
    ps += e;
  }
#pragma unroll
  for (int o=32;o>0;o>>=1) ps += __shfl_down(ps,o);
  if ((tid&63)==0) sm[tid>>6]=ps;
  __syncthreads();
  if (tid==0){
    float s=0.f;
#pragma unroll
    for (int w=0;w<16;w++) s+=sm[w];
    denom[b]=s;
  }
}

// attn-pool partials of xn
__global__ __launch_bounds__(256) void vpool_partial(const u16* __restrict__ xn,
    const float* __restrict__ e, float* __restrict__ pv)
{
  const int c = blockIdx.x*256 + threadIdx.x;
  const int b = blockIdx.y, z = blockIdx.z;
  const int n0 = z*(N_/NSPLIT);
  const u16* vp = xn + ((size_t)b*N_ + n0)*C_ + c;
  const float* ep = e + (size_t)b*N_ + n0;
  float acc=0.f;
  for (int n=0;n<N_/NSPLIT;n++) acc += bf2f(vp[(size_t)n*C_])*ep[n];
  pv[((size_t)z*B_+b)*C_+c] = acc;
}

// pro_fused: vpool_final + qp=vin@Wv + sim + pro + rowx/rowy = pro@Wp*B
__global__ __launch_bounds__(256) void pro_fused(const float* __restrict__ pv,
    const float* __restrict__ denom,
    const float* __restrict__ Wv, const float* __restrict__ Wpx,
    const float* __restrict__ Wpy,
    const float* __restrict__ fg, const float* __restrict__ fgn,
    float* __restrict__ rowx, float* __restrict__ rowy)
{
  __shared__ float vin[C_];
  __shared__ float red[8];
  __shared__ float simsh;
  const int b = blockIdx.x, tid = threadIdx.x;
  const float den = 1.f/denom[b];
  for (int c=tid;c<C_;c+=256){
    float s=0.f;
#pragma unroll
    for (int z=0;z<NSPLIT;z++) s += pv[((size_t)z*B_+b)*C_+c];
    vin[c] = s*den;
  }
  __syncthreads();
  const int j0 = tid, j1 = tid+256, j2 = tid+512;
  float q0=0,q1=0,q2=0;
  for (int c=0;c<C_;c++){
    const float* w = Wv + (size_t)c*C_;
    float vv = vin[c];
    q0 += vv*w[j0]; q1 += vv*w[j1]; q2 += vv*w[j2];
  }
  const float fg0 = fg[b*C_+j0], fg1 = fg[b*C_+j1], fg2 = fg[b*C_+j2];
  float d = q0*fg0 + q1*fg1 + q2*fg2;
  float qq = q0*q0 + q1*q1 + q2*q2;
#pragma unroll
  for (int o=32;o>0;o>>=1){ d+=__shfl_down(d,o); qq+=__shfl_down(qq,o); }
  if ((tid&63)==0){ red[tid>>6]=d; red[4+(tid>>6)]=qq; }
  __syncthreads();
  if (tid==0){
    float dd=red[0]+red[1]+red[2]+red[3], qs=red[4]+red[5]+red[6]+red[7];
    simsh = (dd/(sqrtf(qs)*fgn[b]+1e-7f)+1.f)*0.5f;
  }
  __syncthreads();
  const float sim = simsh;
  vin[j0] = sim*fg0 + (1.f-sim)*q0;
  vin[j1] = sim*fg1 + (1.f-sim)*q1;
  vin[j2] = sim*fg2 + (1.f-sim)*q2;
  __syncthreads();
  float rx0=0,rx1=0,rx2=0, ry0=0,ry1=0,ry2=0;
  for (int c=0;c<C_;c++){
    const float* wx = Wpx + (size_t)(C_+c)*C_;
    const float* wy = Wpy + (size_t)(C_+c)*C_;
    float pc = vin[c];
    rx0 += pc*wx[j0]; rx1 += pc*wx[j1]; rx2 += pc*wx[j2];
    ry0 += pc*wy[j0]; ry1 += pc*wy[j1]; ry2 += pc*wy[j2];
  }
  rowx[b*C_+j0]=rx0; rowx[b*C_+j1]=rx1; rowx[b*C_+j2]=rx2;
  rowy[b*C_+j0]=ry0; rowy[b*C_+j1]=ry1; rowy[b*C_+j2]=ry2;
}

// ---------------- launcher ----------------
extern "C" void kernel_launch(void* const* d_in, const int* in_sizes, int n_in,
                              void* d_out, int out_size, void* d_ws, size_t ws_size,
                              hipStream_t stream)
{
  const float* x     = (const float*)d_in[0];
  const float* y     = (const float*)d_in[1];
  const float* mask  = (const float*)d_in[2];
  const float* ln1_g = (const float*)d_in[5];
  const float* ln1_b = (const float*)d_in[6];
  const float* Wq    = (const float*)d_in[7];
  const float* Wk    = (const float*)d_in[8];
  const float* Wv    = (const float*)d_in[9];
  const float* Wpx   = (const float*)d_in[10];
  const float* Wpy   = (const float*)d_in[11];
  const float* ln2_g = (const float*)d_in[12];
  const float* ln2_b = (const float*)d_in[13];
  const float* fx1_w = (const float*)d_in[14];
  const float* fx1_b = (const float*)d_in[15];
  const float* fx2_w = (const float*)d_in[16];
  const float* fx2_b = (const float*)d_in[17];
  const float* fy1_w = (const float*)d_in[18];
  const float* fy1_b = (const float*)d_in[19];
  const float* fy2_w = (const float*)d_in[20];
  const float* fy2_b = (const float*)d_in[21];

  float* out    = (float*)d_out;
  float* out_xo = out;
  float* out_yo = out + (size_t)M_*C_;
  float* out_ps = out + 2*(size_t)M_*C_;

  char* ws = (char*)d_ws;
  const size_t ACT = (size_t)M_*C_;
  u16* R0  = (u16*)ws;
  u16* xnb = R0;                           // slot0: xn
  u16* ynb = R0 + ACT;                     // slot1: yn
  u16* kb  = R0 + 2*ACT;                   // slot2: k
  u16* xb  = R0 + 3*ACT;                   // slot3: x bf16 (dead after proj-x)
  u16* yb  = (u16*)(ws + 4*ACT*2);         // slot4: y bf16 (dead after proj-y)
  u16* qb  = yb;                           // slot4 reused: ln2 out
  u16* hid = R0;                           // MLP hidden aliases slots 0-3
  u16* wp  = (u16*)(ws + 5*ACT*2);
  u16* WkT  = wp;
  u16* WpxT = wp + 1*589824;
  u16* WpyT = wp + 2*589824;
  u16* fx1T = wp + 3*589824;
  u16* fx2T = fx1T + 2359296;
  u16* fy1T = fx2T + 2359296;
  u16* fy2T = fy1T + 2359296;
  float* st   = (float*)(ws + 5*ACT*2 + (size_t)(3*589824 + 4*2359296)*2);
  float* fgn  = st + 8;
  float* bgn  = st + 16;
  float* denom= st + 24;
  float* mm   = st + 32;
  float* fg   = st + 64;
  float* bg   = st + 6208;
  float* rowx = st + 24640;
  float* rowy = st + 30784;
  float* fg_s = st + 37056;
  float* bg_s = st + 69824;
  float* escr = st + 102592;
  float* pm   = st + 135360;
  float* pa   = st + 233664;
  float* pv   = st + 331968;
  float* mpart= st + 430272;

  dim3 tb(256);
  dim3 tg(512);

  // --- weights -> bf16 [N,K] + LN1(x,y) (also emits raw bf16 x,y) ---
  transpose_all<<<dim3(10944),tb,0,stream>>>(Wk,Wpx,Wpy,fx1_w,fx2_w,fy1_w,fy2_w,
                                             WkT,WpxT,WpyT,fx1T,fx2T,fy1T,fy2T);
  ln_fwd2<<<dim3(M_/4,2),tb,0,stream>>>(x, y, ln1_g, ln1_b, xnb, ynb, xb, yb);

  // --- k GEMM (q,v eliminated by pooling linearity) ---
  gemm_bf16<0,8><<<dim3(128*6),tg,0,stream>>>(xnb, WkT, C_, C_, 6, kb, nullptr,nullptr,nullptr);

  // --- prototypes fg,bg (f32 path) ---
  pool_partial<<<dim3(3,B_,NSPLIT),tb,0,stream>>>(ynb, mask, pm, pa, mpart);
  proto_fused<<<B_,tb,0,stream>>>(pm, pa, mpart, Wq, fg, bg, fgn, bgn);

  // --- cosine scores + softmax weights ---
  score_kernel<<<M_/4,tb,0,stream>>>(kb, fg, bg, fgn, bgn, fg_s, bg_s);
  minmax_kernel<<<B_,tb,0,stream>>>(fg_s, bg_s, mm);
  scorefin_fused<<<B_,dim3(1024),0,stream>>>(fg_s, bg_s, mm, out_ps, escr, denom);

  // --- query_pro path + pro + row-vectors ---
  vpool_partial<<<dim3(3,B_,NSPLIT),tb,0,stream>>>(xnb, escr, pv);
  pro_fused<<<B_,tb,0,stream>>>(pv, denom, Wv, Wpx, Wpy, fg, fgn, rowx, rowy);

  // --- projection GEMMs: out = resid + act@WpA + pro@WpB ---
  gemm_bf16<1,8><<<dim3(128*6),tg,0,stream>>>(xb, WpxT, C_, C_, 6, out_xo, x, rowx, nullptr);
  gemm_bf16<1,8><<<dim3(128*6),tg,0,stream>>>(yb, WpyT, C_, C_, 6, out_yo, y, rowy, nullptr);

  // --- x MLP ---
  ln_fwd<<<M_/4,tb,0,stream>>>(out_xo, ln2_g, ln2_b, qb);
  gemm_bf16<2,8><<<dim3(128*24),tg,0,stream>>>(qb, fx1T, C_, H_, 24, hid, nullptr,nullptr, fx1_b);
  gemm_bf16<3,2><<<dim3(128*6),tg,0,stream>>>(hid, fx2T, H_, C_, 6, out_xo, nullptr,nullptr, fx2_b);

  // --- y MLP ---
  ln_fwd<<<M_/4,tb,0,stream>>>(out_yo, ln2_g, ln2_b, qb);
  gemm_bf16<2,8><<<dim3(128*24),tg,0,stream>>>(qb, fy1T, C_, H_, 24, hid, nullptr,nullptr, fy1_b);
  gemm_bf16<3,2><<<dim3(128*6),tg,0,stream>>>(hid, fy2T, H_, C_, 6, out_yo, nullptr,nullptr, fy2_b);
}